// Round 3
// baseline (10104.489 us; speedup 1.0000x reference)
//
#include <hip/hip_runtime.h>
#include <math.h>

// ---------------- problem constants ----------------
constexpr int Bc = 32, Cch = 3, Hh = 224, Ww = 224, Pp = 16;
constexpr int Dd = 768, NH = 12, DHd = 64, INNERc = 768;
constexpr int DEPTHc = 12, NCLS = 1000;
constexpr int NPc = 196, Nn = 197, PD = 768;
constexpr float EPSf = 1e-5f;

typedef _Float16 half_t;
typedef __attribute__((ext_vector_type(8))) _Float16 half8;
typedef __attribute__((ext_vector_type(4))) float f32x4;

// ---------------- reduction helpers ----------------
__device__ __forceinline__ float wave_red_sum(float v) {
#pragma unroll
    for (int m = 32; m; m >>= 1) v += __shfl_xor(v, m);
    return v;
}

__device__ __forceinline__ void block_red2(float& s, float& s2, float* red) {
    s = wave_red_sum(s);
    s2 = wave_red_sum(s2);
    int wid = threadIdx.x >> 6, lane = threadIdx.x & 63;
    if (lane == 0) { red[wid] = s; red[4 + wid] = s2; }
    __syncthreads();
    s = red[0] + red[1] + red[2] + red[3];
    s2 = red[4] + red[5] + red[6] + red[7];
}

// ---------------- patchify + patch LN -> f16 ----------------
__global__ __launch_bounds__(256) void k_patch_ln(
        const float* __restrict__ img, const float* __restrict__ g,
        const float* __restrict__ bb, half_t* __restrict__ out) {
    int pid = blockIdx.x;
    int b = pid / NPc, n = pid % NPc;
    int ph = n / 14, pw = n % 14;
    int t = threadIdx.x;
    __shared__ float red[8];
    float v[3];
#pragma unroll
    for (int i = 0; i < 3; i++) {
        int d = t + i * 256;
        int c = d % 3, q = (d / 3) & 15, p = d / 48;
        v[i] = img[((long)(b * Cch + c) * Hh + ph * Pp + p) * Ww + pw * Pp + q];
    }
    float s = v[0] + v[1] + v[2];
    float s2 = v[0] * v[0] + v[1] * v[1] + v[2] * v[2];
    block_red2(s, s2, red);
    float mu = s * (1.f / PD);
    float var = s2 * (1.f / PD) - mu * mu;
    float r = rsqrtf(var + EPSf);
#pragma unroll
    for (int i = 0; i < 3; i++) {
        int d = t + i * 256;
        out[(long)pid * PD + d] = (half_t)((v[i] - mu) * r * g[d] + bb[d]);
    }
}

// ---------------- row LayerNorm (768 wide), templated output ----------------
template <typename T>
__global__ __launch_bounds__(256) void k_ln(
        const float* __restrict__ in, const float* __restrict__ g,
        const float* __restrict__ bb, T* __restrict__ out,
        long in_stride, long out_stride) {
    long row = blockIdx.x;
    const float* ip = in + row * in_stride;
    T* op = out + row * out_stride;
    int t = threadIdx.x;
    __shared__ float red[8];
    float v[3];
#pragma unroll
    for (int i = 0; i < 3; i++) v[i] = ip[t + i * 256];
    float s = v[0] + v[1] + v[2];
    float s2 = v[0] * v[0] + v[1] * v[1] + v[2] * v[2];
    block_red2(s, s2, red);
    float mu = s * (1.f / Dd);
    float var = s2 * (1.f / Dd) - mu * mu;
    float r = rsqrtf(var + EPSf);
#pragma unroll
    for (int i = 0; i < 3; i++) {
        int d = t + i * 256;
        op[d] = (T)((v[i] - mu) * r * g[d] + bb[d]);
    }
}

// ---------------- embed assemble: LN(tmp)+pos, cls+pos ----------------
__global__ __launch_bounds__(256) void k_embed(
        const float* __restrict__ tmp, const float* __restrict__ cls,
        const float* __restrict__ pos, const float* __restrict__ g,
        const float* __restrict__ bb, float* __restrict__ x) {
    int pid = blockIdx.x;
    int b = pid / Nn, n = pid % Nn;
    int t = threadIdx.x;
    float* xp = x + (long)pid * Dd;
    if (n == 0) {
#pragma unroll
        for (int i = 0; i < 3; i++) {
            int d = t + i * 256;
            xp[d] = cls[d] + pos[d];
        }
        return;
    }
    const float* ip = tmp + (long)(b * NPc + n - 1) * Dd;
    __shared__ float red[8];
    float v[3];
#pragma unroll
    for (int i = 0; i < 3; i++) v[i] = ip[t + i * 256];
    float s = v[0] + v[1] + v[2];
    float s2 = v[0] * v[0] + v[1] * v[1] + v[2] * v[2];
    block_red2(s, s2, red);
    float mu = s * (1.f / Dd);
    float var = s2 * (1.f / Dd) - mu * mu;
    float r = rsqrtf(var + EPSf);
#pragma unroll
    for (int i = 0; i < 3; i++) {
        int d = t + i * 256;
        xp[d] = (v[i] - mu) * r * g[d] + bb[d] + pos[(long)n * Dd + d];
    }
}

// ---------------- weight prep: fp32 W[K][N] -> f16 Wt[N][K] ----------------
__global__ __launch_bounds__(256) void k_wprep(
        const float* __restrict__ W, half_t* __restrict__ Wt, int K, int N) {
    W += (long)blockIdx.z * K * N;
    Wt += (long)blockIdx.z * K * N;
    __shared__ float tile[32][33];
    int n = blockIdx.x * 32 + threadIdx.x;
    int k0 = blockIdx.y * 32;
#pragma unroll
    for (int i = 0; i < 4; i++)
        tile[threadIdx.y + i * 8][threadIdx.x] = W[(long)(k0 + threadIdx.y + i * 8) * N + n];
    __syncthreads();
    int kk = k0 + threadIdx.x;
#pragma unroll
    for (int i = 0; i < 4; i++)
        Wt[(long)(blockIdx.x * 32 + threadIdx.y + i * 8) * K + kk] =
            (half_t)tile[threadIdx.x][threadIdx.y + i * 8];
}

// ---------------- f16 MFMA GEMM: C(MxN) = A(MxK f16) @ Bt(NxK f16)^T ----------------
// 128x128 tile, BK=64, 256 thr (4 waves, each 64x64). XOR-swizzled LDS (G4).
// XCD-chunked block swizzle (m204, T1). CT=half_t: LDS-staged coalesced f16 write.
__device__ __forceinline__ half8 lds_frag(const uint4 (*L)[8], int row, int slot) {
    union { uint4 u; half8 h; } t;
    t.u = L[row][slot];
    return t.h;
}

template <int HASB, int HASR, typename CT>
__global__ __launch_bounds__(256, 2) void k_hgemm(
        const half_t* __restrict__ A, const half_t* __restrict__ Bt,
        const float* __restrict__ bias, const float* __restrict__ res,
        CT* __restrict__ C, int M, int N, int K) {
    __shared__ uint4 smem[2176];   // As[128][8] | Bs[128][8]; epilogue aliases half Cs[128][136]
    uint4 (*As)[8] = (uint4(*)[8])smem;
    uint4 (*Bs)[8] = (uint4(*)[8])(smem + 1024);
    const int tid = threadIdx.x;
    // bijective XCD-chunk swizzle: dispatch id -> contiguous tile chunk per XCD
    const int nwg = gridDim.x;
    const int q8 = nwg >> 3, r8 = nwg & 7;
    const int xc = blockIdx.x & 7, oo = blockIdx.x >> 3;
    const int tile = (xc < r8 ? xc * (q8 + 1) : r8 * (q8 + 1) + (xc - r8) * q8) + oo;
    const int gx = N >> 7;
    const int n0 = (tile % gx) * 128, m0 = (tile / gx) * 128;
    const int lane = tid & 63, w = tid >> 6;
    const int wrr = (w >> 1) * 64, wcc = (w & 1) * 64;
    const int lrow = lane & 15, lgrp = lane >> 4;

    int lm[4], sw[4];
    long gA[4], gB[4];
    const int cb = (tid & 7) * 8;
#pragma unroll
    for (int c = 0; c < 4; ++c) {
        lm[c] = c * 32 + (tid >> 3);
        sw[c] = (tid & 7) ^ (lm[c] & 7);
        int ma = m0 + lm[c];
        if (ma > M - 1) ma = M - 1;
        gA[c] = (long)ma * K + cb;
        gB[c] = (long)(n0 + lm[c]) * K + cb;  // N always multiple of 128
    }

    f32x4 acc[4][4] = {};
    uint4 ra[4], rb[4];
#pragma unroll
    for (int c = 0; c < 4; ++c) { ra[c] = *(const uint4*)(A + gA[c]); rb[c] = *(const uint4*)(Bt + gB[c]); }
#pragma unroll
    for (int c = 0; c < 4; ++c) { As[lm[c]][sw[c]] = ra[c]; Bs[lm[c]][sw[c]] = rb[c]; }
    __syncthreads();

    const int nst = K >> 6;
    for (int t = 0; t < nst; ++t) {
        if (t + 1 < nst) {
            const int k0 = (t + 1) << 6;
#pragma unroll
            for (int c = 0; c < 4; ++c) {
                ra[c] = *(const uint4*)(A + gA[c] + k0);
                rb[c] = *(const uint4*)(Bt + gB[c] + k0);
            }
        }
#pragma unroll
        for (int kh = 0; kh < 2; ++kh) {
            half8 af[4], bf[4];
#pragma unroll
            for (int i2 = 0; i2 < 4; ++i2) {
                int m = wrr + i2 * 16 + lrow;
                af[i2] = lds_frag(As, m, (kh * 4 + lgrp) ^ (m & 7));
                int n = wcc + i2 * 16 + lrow;
                bf[i2] = lds_frag(Bs, n, (kh * 4 + lgrp) ^ (n & 7));
            }
#pragma unroll
            for (int i2 = 0; i2 < 4; ++i2)
#pragma unroll
                for (int j2 = 0; j2 < 4; ++j2)
                    acc[i2][j2] = __builtin_amdgcn_mfma_f32_16x16x32_f16(af[i2], bf[j2], acc[i2][j2], 0, 0, 0);
        }
        if (t + 1 < nst) {
            __syncthreads();
#pragma unroll
            for (int c = 0; c < 4; ++c) { As[lm[c]][sw[c]] = ra[c]; Bs[lm[c]][sw[c]] = rb[c]; }
            __syncthreads();
        }
    }

    // epilogue: C/D layout col=lane&15, row=(lane>>4)*4+q (m89-verified)
    if constexpr (sizeof(CT) == 2) {
        // stage f16 tile in LDS (stride 136 halves: 16B-aligned rows, conflict-lite), coalesced write
        __syncthreads();
        half_t* Cs = (half_t*)smem;
#pragma unroll
        for (int i2 = 0; i2 < 4; ++i2)
#pragma unroll
            for (int j2 = 0; j2 < 4; ++j2) {
                int colc = wcc + j2 * 16 + lrow;
                float bv = HASB ? bias[n0 + colc] : 0.f;
#pragma unroll
                for (int q = 0; q < 4; ++q) {
                    int r = wrr + i2 * 16 + lgrp * 4 + q;
                    Cs[r * 136 + colc] = (half_t)(acc[i2][j2][q] + bv);
                }
            }
        __syncthreads();
#pragma unroll
        for (int it = 0; it < 8; ++it) {
            int idx = tid + it * 256;
            int row = idx >> 4, cu = idx & 15;
            if (m0 + row < M)
                *(uint4*)(C + (long)(m0 + row) * N + n0 + cu * 8) =
                    *(const uint4*)(Cs + row * 136 + cu * 8);
        }
    } else {
#pragma unroll
        for (int i2 = 0; i2 < 4; ++i2)
#pragma unroll
            for (int j2 = 0; j2 < 4; ++j2) {
                int colc = n0 + wcc + j2 * 16 + lrow;
                float bv = HASB ? bias[colc] : 0.f;
#pragma unroll
                for (int q = 0; q < 4; ++q) {
                    int r = m0 + wrr + i2 * 16 + lgrp * 4 + q;
                    if (r < M) {
                        float v = acc[i2][j2][q] + bv;
                        if (HASR) v += res[(long)r * N + colc];
                        C[(long)r * N + colc] = v;
                    }
                }
            }
    }
}

// ---------------- fp32 tiled GEMM (tiny head GEMM only) ----------------
template <int HASB, int HASR>
__global__ __launch_bounds__(256) void k_gemm(
        const float* __restrict__ A, const float* __restrict__ Wt,
        const float* __restrict__ bias, const float* __restrict__ res,
        float* __restrict__ Co, int M, int Nc, int K) {
    __shared__ float As[16][65];
    __shared__ float Bs[16][68];
    int n0 = blockIdx.x * 64, m0 = blockIdx.y * 64;
    int tid = threadIdx.x;
    int tr = tid / 16, tc = tid % 16;
    int am = tid / 4, ak = (tid % 4) * 4;
    int bk = tid / 16, bn = (tid % 16) * 4;
    float acc[4][4] = {};
    bool nfull = (n0 + 64 <= Nc);
    for (int k0 = 0; k0 < K; k0 += 16) {
        float4 av = {0, 0, 0, 0};
        if (m0 + am < M) av = *(const float4*)&A[(long)(m0 + am) * K + k0 + ak];
        As[ak + 0][am] = av.x; As[ak + 1][am] = av.y;
        As[ak + 2][am] = av.z; As[ak + 3][am] = av.w;
        if (nfull) {
            float4 bv = *(const float4*)&Wt[(long)(k0 + bk) * Nc + n0 + bn];
            Bs[bk][bn + 0] = bv.x; Bs[bk][bn + 1] = bv.y;
            Bs[bk][bn + 2] = bv.z; Bs[bk][bn + 3] = bv.w;
        } else {
#pragma unroll
            for (int u = 0; u < 4; u++)
                Bs[bk][bn + u] = (n0 + bn + u < Nc) ? Wt[(long)(k0 + bk) * Nc + n0 + bn + u] : 0.f;
        }
        __syncthreads();
#pragma unroll
        for (int kk = 0; kk < 16; kk++) {
            float a0 = As[kk][tr * 4 + 0], a1 = As[kk][tr * 4 + 1];
            float a2 = As[kk][tr * 4 + 2], a3 = As[kk][tr * 4 + 3];
            float b0 = Bs[kk][tc], b1 = Bs[kk][tc + 16];
            float b2 = Bs[kk][tc + 32], b3 = Bs[kk][tc + 48];
            acc[0][0] += a0 * b0; acc[0][1] += a0 * b1; acc[0][2] += a0 * b2; acc[0][3] += a0 * b3;
            acc[1][0] += a1 * b0; acc[1][1] += a1 * b1; acc[1][2] += a1 * b2; acc[1][3] += a1 * b3;
            acc[2][0] += a2 * b0; acc[2][1] += a2 * b1; acc[2][2] += a2 * b2; acc[2][3] += a2 * b3;
            acc[3][0] += a3 * b0; acc[3][1] += a3 * b1; acc[3][2] += a3 * b2; acc[3][3] += a3 * b3;
        }
        __syncthreads();
    }
#pragma unroll
    for (int i = 0; i < 4; i++) {
        int r = m0 + tr * 4 + i;
        if (r >= M) continue;
#pragma unroll
        for (int j = 0; j < 4; j++) {
            int c0 = n0 + tc + j * 16;
            if (c0 >= Nc) continue;
            float v = acc[i][j];
            if (HASB) v += bias[c0];
            if (HASR) v += res[(long)r * Nc + c0];
            Co[(long)r * Nc + c0] = v;
        }
    }
}

// ---------------- fused scores + cross-head norm ----------------
// dw = (q.k)*scale*(1+sph) with scale>0, (1+sph)>0 identical across heads
// => z-score over heads is invariant to that factor => skip it entirely.
// Block: (jt, it, b); thread (ti,tj) owns one (i,j), holds all 12 head dots.
__global__ __launch_bounds__(256) void k_scores_hn(
        const half_t* __restrict__ qkv, half_t* __restrict__ dots) {
    const int b = blockIdx.z;
    const int i0 = blockIdx.y * 16, j0 = blockIdx.x * 16;
    __shared__ half_t qs[16][72], ks[16][72];
    const int tid = threadIdx.x;
    const int ti = tid >> 4, tj = tid & 15;
    const int i = i0 + ti, j = j0 + tj;
    // staging roles: 128 threads q, 128 threads k; each one half8
    const int side = tid >> 7;
    const int lr = tid & 127;
    const int sr = lr >> 3, sc = (lr & 7) * 8;
    int rq = i0 + sr; if (rq > Nn - 1) rq = Nn - 1;
    int rk = j0 + sr; if (rk > Nn - 1) rk = Nn - 1;
    const long baseq = ((long)(b * Nn + rq)) * 2304 + sc;
    const long basek = ((long)(b * Nn + rk)) * 2304 + INNERc + sc;

    float s[NH];
#pragma unroll
    for (int h = 0; h < NH; h++) {
        __syncthreads();
        if (side == 0) *(half8*)&qs[sr][sc] = *(const half8*)&qkv[baseq + h * 64];
        else           *(half8*)&ks[sr][sc] = *(const half8*)&qkv[basek + h * 64];
        __syncthreads();
        float acc = 0.f;
#pragma unroll
        for (int k = 0; k < 64; k += 8) {
            half8 qv = *(const half8*)&qs[ti][k];
            half8 kv = *(const half8*)&ks[tj][k];
#pragma unroll
            for (int u = 0; u < 8; u++) acc += (float)qv[u] * (float)kv[u];
        }
        s[h] = acc;
    }
    // cross-head z-score (ddof=1)
    float mu = 0.f;
#pragma unroll
    for (int h = 0; h < NH; h++) mu += s[h];
    mu *= (1.f / NH);
    float s2 = 0.f;
#pragma unroll
    for (int h = 0; h < NH; h++) { float d = s[h] - mu; s2 += d * d; }
    float rs = rsqrtf(s2 * (1.f / (NH - 1)));
    if (i < Nn && j < Nn) {
        long base = ((long)(b * NH) * Nn + i) * Nn + j;
#pragma unroll
        for (int h = 0; h < NH; h++)
            dots[base + (long)h * Nn * Nn] = (half_t)((s[h] - mu) * rs);
    }
}

// ---------------- fused row softmax + attn@V ----------------
// Block: (it, b*NH). 16 q-rows; P kept in LDS; V staged per j-tile; o written f16.
__global__ __launch_bounds__(256) void k_sm_av(
        const half_t* __restrict__ dots, const half_t* __restrict__ qkv,
        half_t* __restrict__ o) {
    const int bh = blockIdx.y;
    const int b = bh / NH, h = bh % NH;
    const int i0 = blockIdx.x * 16;
    __shared__ float P[16][208];
    __shared__ half_t vs[16][72];
    __shared__ float invr[16];
    const int tid = threadIdx.x;
    const int r = tid >> 4, c0 = tid & 15;

    int ri = i0 + r; if (ri > Nn - 1) ri = Nn - 1;
    const half_t* dp = dots + ((long)bh * Nn + ri) * Nn;
    float vbuf[13];
    float mx = -1e30f;
#pragma unroll
    for (int t = 0; t < 13; t++) {
        int j = c0 + t * 16;
        float v = (j < Nn) ? (float)dp[j] : -1e30f;
        vbuf[t] = v;
        mx = fmaxf(mx, v);
    }
    mx = fmaxf(mx, __shfl_xor(mx, 1));
    mx = fmaxf(mx, __shfl_xor(mx, 2));
    mx = fmaxf(mx, __shfl_xor(mx, 4));
    mx = fmaxf(mx, __shfl_xor(mx, 8));
    float sum = 0.f;
#pragma unroll
    for (int t = 0; t < 13; t++) {
        int j = c0 + t * 16;
        float v = (j < Nn) ? __expf(vbuf[t] - mx) : 0.f;
        P[r][j] = v;
        sum += v;
    }
    sum += __shfl_xor(sum, 1);
    sum += __shfl_xor(sum, 2);
    sum += __shfl_xor(sum, 4);
    sum += __shfl_xor(sum, 8);
    if (c0 == 0) invr[r] = 1.f / sum;
    __syncthreads();

    // AV: thread (ti, td) computes rows ti, cols td + t*16
    const int ti = tid >> 4, td = tid & 15;
    float acc[4] = {0, 0, 0, 0};
    const int vr = tid >> 3, vc = (tid & 7) * 8;   // staging: 128 threads
    for (int jt = 0; jt < 13; jt++) {
        if (tid < 128) {
            int rv = jt * 16 + vr; if (rv > Nn - 1) rv = Nn - 1;
            *(half8*)&vs[vr][vc] =
                *(const half8*)&qkv[((long)(b * Nn + rv)) * 2304 + 2 * INNERc + h * 64 + vc];
        }
        __syncthreads();
#pragma unroll
        for (int jj = 0; jj < 16; jj++) {
            float av = P[ti][jt * 16 + jj];
#pragma unroll
            for (int t = 0; t < 4; t++) acc[t] += av * (float)vs[jj][td + t * 16];
        }
        __syncthreads();
    }
    if (i0 + ti < Nn) {
        float inv = invr[ti];
        half_t* op = o + ((long)(b * Nn + i0 + ti)) * INNERc + h * 64;
#pragma unroll
        for (int t = 0; t < 4; t++) op[td + t * 16] = (half_t)(acc[t] * inv);
    }
}

// ---------------- host launcher ----------------
extern "C" void kernel_launch(void* const* d_in, const int* in_sizes, int n_in,
                              void* d_out, int out_size, void* d_ws, size_t ws_size,
                              hipStream_t stream) {
    const float* img     = (const float*)d_in[0];
    const float* patch_g = (const float*)d_in[2];
    const float* patch_b = (const float*)d_in[3];
    const float* W_patch = (const float*)d_in[4];
    const float* b_patch = (const float*)d_in[5];
    const float* emb_g   = (const float*)d_in[6];
    const float* emb_b   = (const float*)d_in[7];
    const float* pos     = (const float*)d_in[8];
    const float* cls     = (const float*)d_in[9];
    const float* ln_g    = (const float*)d_in[10];
    const float* ln_b    = (const float*)d_in[11];
    const float* W_qkv   = (const float*)d_in[12];
    const float* W_out   = (const float*)d_in[13];
    const float* b_out   = (const float*)d_in[14];
    const float* fin_g   = (const float*)d_in[15];
    const float* fin_b   = (const float*)d_in[16];
    const float* W_head  = (const float*)d_in[17];
    const float* b_head  = (const float*)d_in[18];
    float* out = (float*)d_out;

    const long SZ_XD   = (long)Bc * Nn * Dd;          // 4,841,472
    const long SZ_QKV  = (long)Bc * Nn * 3 * INNERc;  // 14,524,416
    const long SZ_DOTS = (long)Bc * NH * Nn * Nn;     // 14,902,656
    const long SZ_TMP  = (long)Bc * NPc * Dd;         // 4,816,896

    float* x    = (float*)d_ws;
    float* tmp  = x + SZ_XD;                 // patch-embed GEMM out (fp32)
    float* clsb = tmp + SZ_TMP;              // 32x768 fp32
    half_t* xh       = (half_t*)(clsb + 32 * 768);          // f16 LN out / AV out
    half_t* qkvh     = xh + SZ_XD;                          // f16 qkv
    half_t* dotsh    = qkvh + SZ_QKV;                       // f16 normalized dots
    half_t* wt_patch = dotsh + SZ_DOTS;                     // 768x768
    half_t* wt_qkv   = wt_patch + (long)Dd * Dd;            // 12 x 2304x768
    half_t* wt_out   = wt_qkv + (long)DEPTHc * 3 * INNERc * Dd;  // 12 x 768x768

    // ---- weight prep: fp32 [K][N] -> f16 [N][K] ----
    hipLaunchKernelGGL(k_wprep, dim3(Dd / 32, Dd / 32, 1), dim3(32, 8), 0, stream,
                       W_patch, wt_patch, Dd, Dd);
    hipLaunchKernelGGL(k_wprep, dim3(3 * INNERc / 32, Dd / 32, DEPTHc), dim3(32, 8), 0, stream,
                       W_qkv, wt_qkv, Dd, 3 * INNERc);
    hipLaunchKernelGGL(k_wprep, dim3(Dd / 32, Dd / 32, DEPTHc), dim3(32, 8), 0, stream,
                       W_out, wt_out, Dd, Dd);

    // 1. patchify + patch LN -> xh (f16)
    hipLaunchKernelGGL(k_patch_ln, dim3(Bc * NPc), dim3(256), 0, stream,
                       img, patch_g, patch_b, xh);
    // 2. patch GEMM (+b_patch) -> tmp fp32
    hipLaunchKernelGGL((k_hgemm<1, 0, float>), dim3(6 * 49), dim3(256), 0, stream,
                       xh, wt_patch, b_patch, nullptr, tmp, Bc * NPc, Dd, Dd);
    // 3. emb LN + cls concat + pos add -> x
    hipLaunchKernelGGL(k_embed, dim3(Bc * Nn), dim3(256), 0, stream,
                       tmp, cls, pos, emb_g, emb_b, x);

    const int Mrows = Bc * Nn;  // 6304
    for (int l = 0; l < DEPTHc; l++) {
        const float* g  = ln_g + (long)l * Dd;
        const float* bb = ln_b + (long)l * Dd;
        const half_t* Wq = wt_qkv + (long)l * 3 * INNERc * Dd;
        const half_t* Wo = wt_out + (long)l * Dd * Dd;
        const float* bo = b_out + (long)l * Dd;
        hipLaunchKernelGGL((k_ln<half_t>), dim3(Mrows), dim3(256), 0, stream,
                           x, g, bb, xh, (long)Dd, (long)Dd);
        hipLaunchKernelGGL((k_hgemm<0, 0, half_t>), dim3(18 * 50), dim3(256), 0, stream,
                           xh, Wq, nullptr, nullptr, qkvh, Mrows, 3 * INNERc, Dd);
        hipLaunchKernelGGL(k_scores_hn, dim3(13, 13, Bc), dim3(256), 0, stream,
                           qkvh, dotsh);
        hipLaunchKernelGGL(k_sm_av, dim3(13, Bc * NH), dim3(256), 0, stream,
                           dotsh, qkvh, xh);
        hipLaunchKernelGGL((k_hgemm<1, 1, float>), dim3(6 * 50), dim3(256), 0, stream,
                           xh, Wo, bo, x, x, Mrows, Dd, Dd);
    }
    // final LN (cls rows only) -> clsb fp32
    hipLaunchKernelGGL((k_ln<float>), dim3(Bc), dim3(256), 0, stream,
                       x, fin_g, fin_b, clsb, (long)Nn * Dd, (long)Dd);
    // head GEMM (fp32, tiny)
    hipLaunchKernelGGL((k_gemm<1, 0>), dim3(16, 1), dim3(256), 0, stream,
                       clsb, W_head, b_head, nullptr, out, Bc, NCLS, Dd);
}

// Round 4
// 4531.975 us; speedup vs baseline: 2.2296x; 2.2296x over previous
//
#include <hip/hip_runtime.h>
#include <math.h>

// ---------------- problem constants ----------------
constexpr int Bc = 32, Cch = 3, Hh = 224, Ww = 224, Pp = 16;
constexpr int Dd = 768, NH = 12, DHd = 64, INNERc = 768;
constexpr int DEPTHc = 12, NCLS = 1000;
constexpr int NPc = 196, Nn = 197, PD = 768;
constexpr float EPSf = 1e-5f;

typedef _Float16 half_t;
typedef __attribute__((ext_vector_type(8))) _Float16 half8;
typedef __attribute__((ext_vector_type(4))) float f32x4;

// ---------------- reduction helpers ----------------
__device__ __forceinline__ float wave_red_sum(float v) {
#pragma unroll
    for (int m = 32; m; m >>= 1) v += __shfl_xor(v, m);
    return v;
}

__device__ __forceinline__ void block_red2(float& s, float& s2, float* red) {
    s = wave_red_sum(s);
    s2 = wave_red_sum(s2);
    int wid = threadIdx.x >> 6, lane = threadIdx.x & 63;
    if (lane == 0) { red[wid] = s; red[4 + wid] = s2; }
    __syncthreads();
    s = red[0] + red[1] + red[2] + red[3];
    s2 = red[4] + red[5] + red[6] + red[7];
}

// ---------------- patchify + patch LN -> f16 ----------------
__global__ __launch_bounds__(256) void k_patch_ln(
        const float* __restrict__ img, const float* __restrict__ g,
        const float* __restrict__ bb, half_t* __restrict__ out) {
    int pid = blockIdx.x;
    int b = pid / NPc, n = pid % NPc;
    int ph = n / 14, pw = n % 14;
    int t = threadIdx.x;
    __shared__ float red[8];
    float v[3];
#pragma unroll
    for (int i = 0; i < 3; i++) {
        int d = t + i * 256;
        int c = d % 3, q = (d / 3) & 15, p = d / 48;
        v[i] = img[((long)(b * Cch + c) * Hh + ph * Pp + p) * Ww + pw * Pp + q];
    }
    float s = v[0] + v[1] + v[2];
    float s2 = v[0] * v[0] + v[1] * v[1] + v[2] * v[2];
    block_red2(s, s2, red);
    float mu = s * (1.f / PD);
    float var = s2 * (1.f / PD) - mu * mu;
    float r = rsqrtf(var + EPSf);
#pragma unroll
    for (int i = 0; i < 3; i++) {
        int d = t + i * 256;
        out[(long)pid * PD + d] = (half_t)((v[i] - mu) * r * g[d] + bb[d]);
    }
}

// ---------------- row LayerNorm (768 wide), templated output ----------------
template <typename T>
__global__ __launch_bounds__(256) void k_ln(
        const float* __restrict__ in, const float* __restrict__ g,
        const float* __restrict__ bb, T* __restrict__ out,
        long in_stride, long out_stride) {
    long row = blockIdx.x;
    const float* ip = in + row * in_stride;
    T* op = out + row * out_stride;
    int t = threadIdx.x;
    __shared__ float red[8];
    float v[3];
#pragma unroll
    for (int i = 0; i < 3; i++) v[i] = ip[t + i * 256];
    float s = v[0] + v[1] + v[2];
    float s2 = v[0] * v[0] + v[1] * v[1] + v[2] * v[2];
    block_red2(s, s2, red);
    float mu = s * (1.f / Dd);
    float var = s2 * (1.f / Dd) - mu * mu;
    float r = rsqrtf(var + EPSf);
#pragma unroll
    for (int i = 0; i < 3; i++) {
        int d = t + i * 256;
        op[d] = (T)((v[i] - mu) * r * g[d] + bb[d]);
    }
}

// ---------------- embed assemble: LN(tmp)+pos, cls+pos ----------------
__global__ __launch_bounds__(256) void k_embed(
        const float* __restrict__ tmp, const float* __restrict__ cls,
        const float* __restrict__ pos, const float* __restrict__ g,
        const float* __restrict__ bb, float* __restrict__ x) {
    int pid = blockIdx.x;
    int b = pid / Nn, n = pid % Nn;
    int t = threadIdx.x;
    float* xp = x + (long)pid * Dd;
    if (n == 0) {
#pragma unroll
        for (int i = 0; i < 3; i++) {
            int d = t + i * 256;
            xp[d] = cls[d] + pos[d];
        }
        return;
    }
    const float* ip = tmp + (long)(b * NPc + n - 1) * Dd;
    __shared__ float red[8];
    float v[3];
#pragma unroll
    for (int i = 0; i < 3; i++) v[i] = ip[t + i * 256];
    float s = v[0] + v[1] + v[2];
    float s2 = v[0] * v[0] + v[1] * v[1] + v[2] * v[2];
    block_red2(s, s2, red);
    float mu = s * (1.f / Dd);
    float var = s2 * (1.f / Dd) - mu * mu;
    float r = rsqrtf(var + EPSf);
#pragma unroll
    for (int i = 0; i < 3; i++) {
        int d = t + i * 256;
        xp[d] = (v[i] - mu) * r * g[d] + bb[d] + pos[(long)n * Dd + d];
    }
}

// ---------------- weight prep: fp32 W[K][N] -> f16 Wt[N][K] ----------------
__global__ __launch_bounds__(256) void k_wprep(
        const float* __restrict__ W, half_t* __restrict__ Wt, int K, int N) {
    W += (long)blockIdx.z * K * N;
    Wt += (long)blockIdx.z * K * N;
    __shared__ float tile[32][33];
    int n = blockIdx.x * 32 + threadIdx.x;
    int k0 = blockIdx.y * 32;
#pragma unroll
    for (int i = 0; i < 4; i++)
        tile[threadIdx.y + i * 8][threadIdx.x] = W[(long)(k0 + threadIdx.y + i * 8) * N + n];
    __syncthreads();
    int kk = k0 + threadIdx.x;
#pragma unroll
    for (int i = 0; i < 4; i++)
        Wt[(long)(blockIdx.x * 32 + threadIdx.y + i * 8) * K + kk] =
            (half_t)tile[threadIdx.x][threadIdx.y + i * 8];
}

// ---------------- f16 MFMA GEMM: C(MxN) = A(MxK f16) @ Bt(NxK f16)^T ----------------
__device__ __forceinline__ half8 lds_frag(const uint4 (*L)[8], int row, int slot) {
    union { uint4 u; half8 h; } t;
    t.u = L[row][slot];
    return t.h;
}

template <int HASB, int HASR, typename CT>
__global__ __launch_bounds__(256, 2) void k_hgemm(
        const half_t* __restrict__ A, const half_t* __restrict__ Bt,
        const float* __restrict__ bias, const float* __restrict__ res,
        CT* __restrict__ C, int M, int N, int K) {
    __shared__ uint4 smem[2176];   // As[128][8] | Bs[128][8]; epilogue aliases half Cs[128][136]
    uint4 (*As)[8] = (uint4(*)[8])smem;
    uint4 (*Bs)[8] = (uint4(*)[8])(smem + 1024);
    const int tid = threadIdx.x;
    const int nwg = gridDim.x;
    const int q8 = nwg >> 3, r8 = nwg & 7;
    const int xc = blockIdx.x & 7, oo = blockIdx.x >> 3;
    const int tile = (xc < r8 ? xc * (q8 + 1) : r8 * (q8 + 1) + (xc - r8) * q8) + oo;
    const int gx = N >> 7;
    const int n0 = (tile % gx) * 128, m0 = (tile / gx) * 128;
    const int lane = tid & 63, w = tid >> 6;
    const int wrr = (w >> 1) * 64, wcc = (w & 1) * 64;
    const int lrow = lane & 15, lgrp = lane >> 4;

    int lm[4], sw[4];
    long gA[4], gB[4];
    const int cb = (tid & 7) * 8;
#pragma unroll
    for (int c = 0; c < 4; ++c) {
        lm[c] = c * 32 + (tid >> 3);
        sw[c] = (tid & 7) ^ (lm[c] & 7);
        int ma = m0 + lm[c];
        if (ma > M - 1) ma = M - 1;
        gA[c] = (long)ma * K + cb;
        gB[c] = (long)(n0 + lm[c]) * K + cb;
    }

    f32x4 acc[4][4] = {};
    uint4 ra[4], rb[4];
#pragma unroll
    for (int c = 0; c < 4; ++c) { ra[c] = *(const uint4*)(A + gA[c]); rb[c] = *(const uint4*)(Bt + gB[c]); }
#pragma unroll
    for (int c = 0; c < 4; ++c) { As[lm[c]][sw[c]] = ra[c]; Bs[lm[c]][sw[c]] = rb[c]; }
    __syncthreads();

    const int nst = K >> 6;
    for (int t = 0; t < nst; ++t) {
        if (t + 1 < nst) {
            const int k0 = (t + 1) << 6;
#pragma unroll
            for (int c = 0; c < 4; ++c) {
                ra[c] = *(const uint4*)(A + gA[c] + k0);
                rb[c] = *(const uint4*)(Bt + gB[c] + k0);
            }
        }
#pragma unroll
        for (int kh = 0; kh < 2; ++kh) {
            half8 af[4], bf[4];
#pragma unroll
            for (int i2 = 0; i2 < 4; ++i2) {
                int m = wrr + i2 * 16 + lrow;
                af[i2] = lds_frag(As, m, (kh * 4 + lgrp) ^ (m & 7));
                int n = wcc + i2 * 16 + lrow;
                bf[i2] = lds_frag(Bs, n, (kh * 4 + lgrp) ^ (n & 7));
            }
#pragma unroll
            for (int i2 = 0; i2 < 4; ++i2)
#pragma unroll
                for (int j2 = 0; j2 < 4; ++j2)
                    acc[i2][j2] = __builtin_amdgcn_mfma_f32_16x16x32_f16(af[i2], bf[j2], acc[i2][j2], 0, 0, 0);
        }
        if (t + 1 < nst) {
            __syncthreads();
#pragma unroll
            for (int c = 0; c < 4; ++c) { As[lm[c]][sw[c]] = ra[c]; Bs[lm[c]][sw[c]] = rb[c]; }
            __syncthreads();
        }
    }

    if constexpr (sizeof(CT) == 2) {
        __syncthreads();
        half_t* Cs = (half_t*)smem;
#pragma unroll
        for (int i2 = 0; i2 < 4; ++i2)
#pragma unroll
            for (int j2 = 0; j2 < 4; ++j2) {
                int colc = wcc + j2 * 16 + lrow;
                float bv = HASB ? bias[n0 + colc] : 0.f;
#pragma unroll
                for (int q = 0; q < 4; ++q) {
                    int r = wrr + i2 * 16 + lgrp * 4 + q;
                    Cs[r * 136 + colc] = (half_t)(acc[i2][j2][q] + bv);
                }
            }
        __syncthreads();
#pragma unroll
        for (int it = 0; it < 8; ++it) {
            int idx = tid + it * 256;
            int row = idx >> 4, cu = idx & 15;
            if (m0 + row < M)
                *(uint4*)(C + (long)(m0 + row) * N + n0 + cu * 8) =
                    *(const uint4*)(Cs + row * 136 + cu * 8);
        }
    } else {
#pragma unroll
        for (int i2 = 0; i2 < 4; ++i2)
#pragma unroll
            for (int j2 = 0; j2 < 4; ++j2) {
                int colc = n0 + wcc + j2 * 16 + lrow;
                float bv = HASB ? bias[colc] : 0.f;
#pragma unroll
                for (int q = 0; q < 4; ++q) {
                    int r = m0 + wrr + i2 * 16 + lgrp * 4 + q;
                    if (r < M) {
                        float v = acc[i2][j2][q] + bv;
                        if (HASR) v += res[(long)r * N + colc];
                        C[(long)r * N + colc] = v;
                    }
                }
            }
    }
}

// ---------------- fp32 tiled GEMM (tiny head GEMM only) ----------------
template <int HASB, int HASR>
__global__ __launch_bounds__(256) void k_gemm(
        const float* __restrict__ A, const float* __restrict__ Wt,
        const float* __restrict__ bias, const float* __restrict__ res,
        float* __restrict__ Co, int M, int Nc, int K) {
    __shared__ float As[16][65];
    __shared__ float Bs[16][68];
    int n0 = blockIdx.x * 64, m0 = blockIdx.y * 64;
    int tid = threadIdx.x;
    int tr = tid / 16, tc = tid % 16;
    int am = tid / 4, ak = (tid % 4) * 4;
    int bk = tid / 16, bn = (tid % 16) * 4;
    float acc[4][4] = {};
    bool nfull = (n0 + 64 <= Nc);
    for (int k0 = 0; k0 < K; k0 += 16) {
        float4 av = {0, 0, 0, 0};
        if (m0 + am < M) av = *(const float4*)&A[(long)(m0 + am) * K + k0 + ak];
        As[ak + 0][am] = av.x; As[ak + 1][am] = av.y;
        As[ak + 2][am] = av.z; As[ak + 3][am] = av.w;
        if (nfull) {
            float4 bv = *(const float4*)&Wt[(long)(k0 + bk) * Nc + n0 + bn];
            Bs[bk][bn + 0] = bv.x; Bs[bk][bn + 1] = bv.y;
            Bs[bk][bn + 2] = bv.z; Bs[bk][bn + 3] = bv.w;
        } else {
#pragma unroll
            for (int u = 0; u < 4; u++)
                Bs[bk][bn + u] = (n0 + bn + u < Nc) ? Wt[(long)(k0 + bk) * Nc + n0 + bn + u] : 0.f;
        }
        __syncthreads();
#pragma unroll
        for (int kk = 0; kk < 16; kk++) {
            float a0 = As[kk][tr * 4 + 0], a1 = As[kk][tr * 4 + 1];
            float a2 = As[kk][tr * 4 + 2], a3 = As[kk][tr * 4 + 3];
            float b0 = Bs[kk][tc], b1 = Bs[kk][tc + 16];
            float b2 = Bs[kk][tc + 32], b3 = Bs[kk][tc + 48];
            acc[0][0] += a0 * b0; acc[0][1] += a0 * b1; acc[0][2] += a0 * b2; acc[0][3] += a0 * b3;
            acc[1][0] += a1 * b0; acc[1][1] += a1 * b1; acc[1][2] += a1 * b2; acc[1][3] += a1 * b3;
            acc[2][0] += a2 * b0; acc[2][1] += a2 * b1; acc[2][2] += a2 * b2; acc[2][3] += a2 * b3;
            acc[3][0] += a3 * b0; acc[3][1] += a3 * b1; acc[3][2] += a3 * b2; acc[3][3] += a3 * b3;
        }
        __syncthreads();
    }
#pragma unroll
    for (int i = 0; i < 4; i++) {
        int r = m0 + tr * 4 + i;
        if (r >= M) continue;
#pragma unroll
        for (int j = 0; j < 4; j++) {
            int c0 = n0 + tc + j * 16;
            if (c0 >= Nc) continue;
            float v = acc[i][j];
            if (HASB) v += bias[c0];
            if (HASR) v += res[(long)r * Nc + c0];
            Co[(long)r * Nc + c0] = v;
        }
    }
}

// ---------------- scores: raw q.k -> f16 dots[b,h,i,j] ----------------
// sph & 0.125 scale skipped: a positive per-(i,j) factor identical across heads
// cancels exactly in the cross-head z-score (validated R3).
// Block per (b,h,i-tile16): Q staged once, K streamed per j-tile.
__global__ __launch_bounds__(256) void k_scores16(
        const half_t* __restrict__ qkv, half_t* __restrict__ dots) {
    const int bh = blockIdx.y;
    const int b = bh / NH, h = bh % NH;
    const int i0 = blockIdx.x * 16;
    __shared__ half_t qs[16][72], ks[16][72];
    const int tid = threadIdx.x;
    const int ti = tid >> 4, tj = tid & 15;
    if (tid < 128) {
        int sr = tid >> 3, sc = (tid & 7) * 8;
        int rq = i0 + sr; if (rq > Nn - 1) rq = Nn - 1;
        *(half8*)&qs[sr][sc] = *(const half8*)&qkv[((long)(b * Nn + rq)) * 2304 + h * 64 + sc];
    }
    for (int jt = 0; jt < 13; jt++) {
        __syncthreads();
        if (tid < 128) {
            int sr = tid >> 3, sc = (tid & 7) * 8;
            int rk = jt * 16 + sr; if (rk > Nn - 1) rk = Nn - 1;
            *(half8*)&ks[sr][sc] = *(const half8*)&qkv[((long)(b * Nn + rk)) * 2304 + INNERc + h * 64 + sc];
        }
        __syncthreads();
        float acc = 0.f;
#pragma unroll
        for (int k = 0; k < 64; k += 8) {
            half8 qv = *(const half8*)&qs[ti][k];
            half8 kv = *(const half8*)&ks[tj][k];
#pragma unroll
            for (int u = 0; u < 8; u++) acc += (float)qv[u] * (float)kv[u];
        }
        int i = i0 + ti, j = jt * 16 + tj;
        if (i < Nn && j < Nn)
            dots[((long)bh * Nn + i) * Nn + j] = (half_t)acc;
    }
}

// ---------------- cross-head z-score (ddof=1), f16 in-place ----------------
// Block per (b,i); thread = j. Reads/writes coalesced per head (consecutive j).
__global__ __launch_bounds__(256) void k_hn16(half_t* __restrict__ dots) {
    const int i = blockIdx.x, b = blockIdx.y;
    const int j = threadIdx.x;
    if (j >= Nn) return;
    const long hs = (long)Nn * Nn;
    long base = ((long)(b * NH) * Nn + i) * Nn + j;
    float v[NH];
    float mu = 0.f;
#pragma unroll
    for (int h = 0; h < NH; h++) { v[h] = (float)dots[base + h * hs]; mu += v[h]; }
    mu *= (1.f / NH);
    float s2 = 0.f;
#pragma unroll
    for (int h = 0; h < NH; h++) { float d = v[h] - mu; s2 += d * d; }
    float rs = rsqrtf(s2 * (1.f / (NH - 1)));
#pragma unroll
    for (int h = 0; h < NH; h++) dots[base + h * hs] = (half_t)((v[h] - mu) * rs);
}

// ---------------- fused row softmax + attn@V ----------------
__global__ __launch_bounds__(256) void k_sm_av(
        const half_t* __restrict__ dots, const half_t* __restrict__ qkv,
        half_t* __restrict__ o) {
    const int bh = blockIdx.y;
    const int b = bh / NH, h = bh % NH;
    const int i0 = blockIdx.x * 16;
    __shared__ float P[16][208];
    __shared__ half_t vs[16][72];
    __shared__ float invr[16];
    const int tid = threadIdx.x;
    const int r = tid >> 4, c0 = tid & 15;

    int ri = i0 + r; if (ri > Nn - 1) ri = Nn - 1;
    const half_t* dp = dots + ((long)bh * Nn + ri) * Nn;
    float vbuf[13];
    float mx = -1e30f;
#pragma unroll
    for (int t = 0; t < 13; t++) {
        int j = c0 + t * 16;
        float v = (j < Nn) ? (float)dp[j] : -1e30f;
        vbuf[t] = v;
        mx = fmaxf(mx, v);
    }
    mx = fmaxf(mx, __shfl_xor(mx, 1));
    mx = fmaxf(mx, __shfl_xor(mx, 2));
    mx = fmaxf(mx, __shfl_xor(mx, 4));
    mx = fmaxf(mx, __shfl_xor(mx, 8));
    float sum = 0.f;
#pragma unroll
    for (int t = 0; t < 13; t++) {
        int j = c0 + t * 16;
        float v = (j < Nn) ? __expf(vbuf[t] - mx) : 0.f;
        P[r][j] = v;
        sum += v;
    }
    sum += __shfl_xor(sum, 1);
    sum += __shfl_xor(sum, 2);
    sum += __shfl_xor(sum, 4);
    sum += __shfl_xor(sum, 8);
    if (c0 == 0) invr[r] = 1.f / sum;
    __syncthreads();

    const int ti = tid >> 4, td = tid & 15;
    float acc[4] = {0, 0, 0, 0};
    const int vr = tid >> 3, vc = (tid & 7) * 8;
    for (int jt = 0; jt < 13; jt++) {
        if (tid < 128) {
            int rv = jt * 16 + vr; if (rv > Nn - 1) rv = Nn - 1;
            *(half8*)&vs[vr][vc] =
                *(const half8*)&qkv[((long)(b * Nn + rv)) * 2304 + 2 * INNERc + h * 64 + vc];
        }
        __syncthreads();
#pragma unroll
        for (int jj = 0; jj < 16; jj++) {
            float av = P[ti][jt * 16 + jj];
#pragma unroll
            for (int t = 0; t < 4; t++) acc[t] += av * (float)vs[jj][td + t * 16];
        }
        __syncthreads();
    }
    if (i0 + ti < Nn) {
        float inv = invr[ti];
        half_t* op = o + ((long)(b * Nn + i0 + ti)) * INNERc + h * 64;
#pragma unroll
        for (int t = 0; t < 4; t++) op[td + t * 16] = (half_t)(acc[t] * inv);
    }
}

// ---------------- host launcher ----------------
extern "C" void kernel_launch(void* const* d_in, const int* in_sizes, int n_in,
                              void* d_out, int out_size, void* d_ws, size_t ws_size,
                              hipStream_t stream) {
    const float* img     = (const float*)d_in[0];
    const float* patch_g = (const float*)d_in[2];
    const float* patch_b = (const float*)d_in[3];
    const float* W_patch = (const float*)d_in[4];
    const float* b_patch = (const float*)d_in[5];
    const float* emb_g   = (const float*)d_in[6];
    const float* emb_b   = (const float*)d_in[7];
    const float* pos     = (const float*)d_in[8];
    const float* cls     = (const float*)d_in[9];
    const float* ln_g    = (const float*)d_in[10];
    const float* ln_b    = (const float*)d_in[11];
    const float* W_qkv   = (const float*)d_in[12];
    const float* W_out   = (const float*)d_in[13];
    const float* b_out   = (const float*)d_in[14];
    const float* fin_g   = (const float*)d_in[15];
    const float* fin_b   = (const float*)d_in[16];
    const float* W_head  = (const float*)d_in[17];
    const float* b_head  = (const float*)d_in[18];
    float* out = (float*)d_out;

    const long SZ_XD   = (long)Bc * Nn * Dd;
    const long SZ_QKV  = (long)Bc * Nn * 3 * INNERc;
    const long SZ_DOTS = (long)Bc * NH * Nn * Nn;
    const long SZ_TMP  = (long)Bc * NPc * Dd;

    float* x    = (float*)d_ws;
    float* tmp  = x + SZ_XD;
    float* clsb = tmp + SZ_TMP;
    half_t* xh       = (half_t*)(clsb + 32 * 768);
    half_t* qkvh     = xh + SZ_XD;
    half_t* dotsh    = qkvh + SZ_QKV;
    half_t* wt_patch = dotsh + SZ_DOTS;
    half_t* wt_qkv   = wt_patch + (long)Dd * Dd;
    half_t* wt_out   = wt_qkv + (long)DEPTHc * 3 * INNERc * Dd;

    // ---- weight prep: fp32 [K][N] -> f16 [N][K] ----
    hipLaunchKernelGGL(k_wprep, dim3(Dd / 32, Dd / 32, 1), dim3(32, 8), 0, stream,
                       W_patch, wt_patch, Dd, Dd);
    hipLaunchKernelGGL(k_wprep, dim3(3 * INNERc / 32, Dd / 32, DEPTHc), dim3(32, 8), 0, stream,
                       W_qkv, wt_qkv, Dd, 3 * INNERc);
    hipLaunchKernelGGL(k_wprep, dim3(Dd / 32, Dd / 32, DEPTHc), dim3(32, 8), 0, stream,
                       W_out, wt_out, Dd, Dd);

    // 1. patchify + patch LN -> xh (f16)
    hipLaunchKernelGGL(k_patch_ln, dim3(Bc * NPc), dim3(256), 0, stream,
                       img, patch_g, patch_b, xh);
    // 2. patch GEMM (+b_patch) -> tmp fp32
    hipLaunchKernelGGL((k_hgemm<1, 0, float>), dim3(6 * 49), dim3(256), 0, stream,
                       xh, wt_patch, b_patch, nullptr, tmp, Bc * NPc, Dd, Dd);
    // 3. emb LN + cls concat + pos add -> x
    hipLaunchKernelGGL(k_embed, dim3(Bc * Nn), dim3(256), 0, stream,
                       tmp, cls, pos, emb_g, emb_b, x);

    const int Mrows = Bc * Nn;  // 6304
    for (int l = 0; l < DEPTHc; l++) {
        const float* g  = ln_g + (long)l * Dd;
        const float* bb = ln_b + (long)l * Dd;
        const half_t* Wq = wt_qkv + (long)l * 3 * INNERc * Dd;
        const half_t* Wo = wt_out + (long)l * Dd * Dd;
        const float* bo = b_out + (long)l * Dd;
        hipLaunchKernelGGL((k_ln<half_t>), dim3(Mrows), dim3(256), 0, stream,
                           x, g, bb, xh, (long)Dd, (long)Dd);
        hipLaunchKernelGGL((k_hgemm<0, 0, half_t>), dim3(18 * 50), dim3(256), 0, stream,
                           xh, Wq, nullptr, nullptr, qkvh, Mrows, 3 * INNERc, Dd);
        hipLaunchKernelGGL(k_scores16, dim3(13, Bc * NH), dim3(256), 0, stream,
                           qkvh, dotsh);
        hipLaunchKernelGGL(k_hn16, dim3(Nn, Bc), dim3(256), 0, stream,
                           dotsh);
        hipLaunchKernelGGL(k_sm_av, dim3(13, Bc * NH), dim3(256), 0, stream,
                           dotsh, qkvh, xh);
        hipLaunchKernelGGL((k_hgemm<1, 1, float>), dim3(6 * 50), dim3(256), 0, stream,
                           xh, Wo, bo, x, x, Mrows, Dd, Dd);
    }
    // final LN (cls rows only) -> clsb fp32
    hipLaunchKernelGGL((k_ln<float>), dim3(Bc), dim3(256), 0, stream,
                       x, fin_g, fin_b, clsb, (long)Nn * Dd, (long)Dd);
    // head GEMM (fp32, tiny)
    hipLaunchKernelGGL((k_gemm<1, 0>), dim3(16, 1), dim3(256), 0, stream,
                       clsb, W_head, b_head, nullptr, out, Bc, NCLS, Dd);
}

// Round 5
// 2829.543 us; speedup vs baseline: 3.5711x; 1.6017x over previous
//
#include <hip/hip_runtime.h>
#include <math.h>

// ---------------- problem constants ----------------
constexpr int Bc = 32, Cch = 3, Hh = 224, Ww = 224, Pp = 16;
constexpr int Dd = 768, NH = 12, DHd = 64, INNERc = 768;
constexpr int DEPTHc = 12, NCLS = 1000;
constexpr int NPc = 196, Nn = 197, PD = 768;
constexpr float EPSf = 1e-5f;

typedef _Float16 half_t;
typedef __attribute__((ext_vector_type(8))) _Float16 half8;
typedef __attribute__((ext_vector_type(4))) float f32x4;
typedef __attribute__((ext_vector_type(4))) unsigned int uint32x4;

// ---------------- reduction helpers ----------------
__device__ __forceinline__ float wave_red_sum(float v) {
#pragma unroll
    for (int m = 32; m; m >>= 1) v += __shfl_xor(v, m);
    return v;
}

__device__ __forceinline__ void block_red2(float& s, float& s2, float* red) {
    s = wave_red_sum(s);
    s2 = wave_red_sum(s2);
    int wid = threadIdx.x >> 6, lane = threadIdx.x & 63;
    if (lane == 0) { red[wid] = s; red[4 + wid] = s2; }
    __syncthreads();
    s = red[0] + red[1] + red[2] + red[3];
    s2 = red[4] + red[5] + red[6] + red[7];
}

// ---------------- patchify + patch LN -> f16 ----------------
__global__ __launch_bounds__(256) void k_patch_ln(
        const float* __restrict__ img, const float* __restrict__ g,
        const float* __restrict__ bb, half_t* __restrict__ out) {
    int pid = blockIdx.x;
    int b = pid / NPc, n = pid % NPc;
    int ph = n / 14, pw = n % 14;
    int t = threadIdx.x;
    __shared__ float red[8];
    float v[3];
#pragma unroll
    for (int i = 0; i < 3; i++) {
        int d = t + i * 256;
        int c = d % 3, q = (d / 3) & 15, p = d / 48;
        v[i] = img[((long)(b * Cch + c) * Hh + ph * Pp + p) * Ww + pw * Pp + q];
    }
    float s = v[0] + v[1] + v[2];
    float s2 = v[0] * v[0] + v[1] * v[1] + v[2] * v[2];
    block_red2(s, s2, red);
    float mu = s * (1.f / PD);
    float var = s2 * (1.f / PD) - mu * mu;
    float r = rsqrtf(var + EPSf);
#pragma unroll
    for (int i = 0; i < 3; i++) {
        int d = t + i * 256;
        out[(long)pid * PD + d] = (half_t)((v[i] - mu) * r * g[d] + bb[d]);
    }
}

// ---------------- row LayerNorm (768 wide), templated output ----------------
template <typename T>
__global__ __launch_bounds__(256) void k_ln(
        const float* __restrict__ in, const float* __restrict__ g,
        const float* __restrict__ bb, T* __restrict__ out,
        long in_stride, long out_stride) {
    long row = blockIdx.x;
    const float* ip = in + row * in_stride;
    T* op = out + row * out_stride;
    int t = threadIdx.x;
    __shared__ float red[8];
    float v[3];
#pragma unroll
    for (int i = 0; i < 3; i++) v[i] = ip[t + i * 256];
    float s = v[0] + v[1] + v[2];
    float s2 = v[0] * v[0] + v[1] * v[1] + v[2] * v[2];
    block_red2(s, s2, red);
    float mu = s * (1.f / Dd);
    float var = s2 * (1.f / Dd) - mu * mu;
    float r = rsqrtf(var + EPSf);
#pragma unroll
    for (int i = 0; i < 3; i++) {
        int d = t + i * 256;
        op[d] = (T)((v[i] - mu) * r * g[d] + bb[d]);
    }
}

// ---------------- embed assemble: LN(tmp)+pos, cls+pos ----------------
__global__ __launch_bounds__(256) void k_embed(
        const float* __restrict__ tmp, const float* __restrict__ cls,
        const float* __restrict__ pos, const float* __restrict__ g,
        const float* __restrict__ bb, float* __restrict__ x) {
    int pid = blockIdx.x;
    int b = pid / Nn, n = pid % Nn;
    int t = threadIdx.x;
    float* xp = x + (long)pid * Dd;
    if (n == 0) {
#pragma unroll
        for (int i = 0; i < 3; i++) {
            int d = t + i * 256;
            xp[d] = cls[d] + pos[d];
        }
        return;
    }
    const float* ip = tmp + (long)(b * NPc + n - 1) * Dd;
    __shared__ float red[8];
    float v[3];
#pragma unroll
    for (int i = 0; i < 3; i++) v[i] = ip[t + i * 256];
    float s = v[0] + v[1] + v[2];
    float s2 = v[0] * v[0] + v[1] * v[1] + v[2] * v[2];
    block_red2(s, s2, red);
    float mu = s * (1.f / Dd);
    float var = s2 * (1.f / Dd) - mu * mu;
    float r = rsqrtf(var + EPSf);
#pragma unroll
    for (int i = 0; i < 3; i++) {
        int d = t + i * 256;
        xp[d] = (v[i] - mu) * r * g[d] + bb[d] + pos[(long)n * Dd + d];
    }
}

// ---------------- weight prep: fp32 W[K][N] -> f16 Wt[N][K] ----------------
__global__ __launch_bounds__(256) void k_wprep(
        const float* __restrict__ W, half_t* __restrict__ Wt, int K, int N) {
    W += (long)blockIdx.z * K * N;
    Wt += (long)blockIdx.z * K * N;
    __shared__ float tile[32][33];
    int n = blockIdx.x * 32 + threadIdx.x;
    int k0 = blockIdx.y * 32;
#pragma unroll
    for (int i = 0; i < 4; i++)
        tile[threadIdx.y + i * 8][threadIdx.x] = W[(long)(k0 + threadIdx.y + i * 8) * N + n];
    __syncthreads();
    int kk = k0 + threadIdx.x;
#pragma unroll
    for (int i = 0; i < 4; i++)
        Wt[(long)(blockIdx.x * 32 + threadIdx.y + i * 8) * K + kk] =
            (half_t)tile[threadIdx.x][threadIdx.y + i * 8];
}

// ---------------- f16 MFMA GEMM: C(MxN) = A(MxK f16) @ Bt(NxK f16)^T ----------------
// OMODE 0: row-major C.  OMODE 1 (f16 only): qkv split to head-major [b,h,n,64]
// C=q, C1=k, C2=v. Non-temporal C stores (write-amplification experiment).
__device__ __forceinline__ half8 lds_frag(const uint32x4 (*L)[8], int row, int slot) {
    union { uint32x4 u; half8 h; } t;
    t.u = L[row][slot];
    return t.h;
}

template <int HASB, int HASR, typename CT, int OMODE>
__global__ __launch_bounds__(256, 2) void k_hgemm(
        const half_t* __restrict__ A, const half_t* __restrict__ Bt,
        const float* __restrict__ bias, const float* __restrict__ res,
        CT* __restrict__ C, CT* __restrict__ C1, CT* __restrict__ C2,
        int M, int N, int K) {
    __shared__ uint32x4 smem[2176];   // As[128][8] | Bs[128][8]; epilogue aliases half Cs
    uint32x4 (*As)[8] = (uint32x4(*)[8])smem;
    uint32x4 (*Bs)[8] = (uint32x4(*)[8])(smem + 1024);
    const int tid = threadIdx.x;
    const int nwg = gridDim.x;
    const int q8 = nwg >> 3, r8 = nwg & 7;
    const int xc = blockIdx.x & 7, oo = blockIdx.x >> 3;
    const int tile = (xc < r8 ? xc * (q8 + 1) : r8 * (q8 + 1) + (xc - r8) * q8) + oo;
    const int gx = N >> 7;
    const int n0 = (tile % gx) * 128, m0 = (tile / gx) * 128;
    const int lane = tid & 63, w = tid >> 6;
    const int wrr = (w >> 1) * 64, wcc = (w & 1) * 64;
    const int lrow = lane & 15, lgrp = lane >> 4;

    int lm[4], sw[4];
    long gA[4], gB[4];
    const int cb = (tid & 7) * 8;
#pragma unroll
    for (int c = 0; c < 4; ++c) {
        lm[c] = c * 32 + (tid >> 3);
        sw[c] = (tid & 7) ^ (lm[c] & 7);
        int ma = m0 + lm[c];
        if (ma > M - 1) ma = M - 1;
        gA[c] = (long)ma * K + cb;
        gB[c] = (long)(n0 + lm[c]) * K + cb;
    }

    f32x4 acc[4][4] = {};
    uint32x4 ra[4], rb[4];
#pragma unroll
    for (int c = 0; c < 4; ++c) { ra[c] = *(const uint32x4*)(A + gA[c]); rb[c] = *(const uint32x4*)(Bt + gB[c]); }
#pragma unroll
    for (int c = 0; c < 4; ++c) { As[lm[c]][sw[c]] = ra[c]; Bs[lm[c]][sw[c]] = rb[c]; }
    __syncthreads();

    const int nst = K >> 6;
    for (int t = 0; t < nst; ++t) {
        if (t + 1 < nst) {
            const int k0 = (t + 1) << 6;
#pragma unroll
            for (int c = 0; c < 4; ++c) {
                ra[c] = *(const uint32x4*)(A + gA[c] + k0);
                rb[c] = *(const uint32x4*)(Bt + gB[c] + k0);
            }
        }
#pragma unroll
        for (int kh = 0; kh < 2; ++kh) {
            half8 af[4], bf[4];
#pragma unroll
            for (int i2 = 0; i2 < 4; ++i2) {
                int m = wrr + i2 * 16 + lrow;
                af[i2] = lds_frag(As, m, (kh * 4 + lgrp) ^ (m & 7));
                int n = wcc + i2 * 16 + lrow;
                bf[i2] = lds_frag(Bs, n, (kh * 4 + lgrp) ^ (n & 7));
            }
#pragma unroll
            for (int i2 = 0; i2 < 4; ++i2)
#pragma unroll
                for (int j2 = 0; j2 < 4; ++j2)
                    acc[i2][j2] = __builtin_amdgcn_mfma_f32_16x16x32_f16(af[i2], bf[j2], acc[i2][j2], 0, 0, 0);
        }
        if (t + 1 < nst) {
            __syncthreads();
#pragma unroll
            for (int c = 0; c < 4; ++c) { As[lm[c]][sw[c]] = ra[c]; Bs[lm[c]][sw[c]] = rb[c]; }
            __syncthreads();
        }
    }

    if constexpr (sizeof(CT) == 2) {
        __syncthreads();
        half_t* Cs = (half_t*)smem;
#pragma unroll
        for (int i2 = 0; i2 < 4; ++i2)
#pragma unroll
            for (int j2 = 0; j2 < 4; ++j2) {
                int colc = wcc + j2 * 16 + lrow;
                float bv = HASB ? bias[n0 + colc] : 0.f;
#pragma unroll
                for (int q = 0; q < 4; ++q) {
                    int r = wrr + i2 * 16 + lgrp * 4 + q;
                    Cs[r * 136 + colc] = (half_t)(acc[i2][j2][q] + bv);
                }
            }
        __syncthreads();
#pragma unroll
        for (int it = 0; it < 8; ++it) {
            int idx = tid + it * 256;
            int row = idx >> 4, cu = idx & 15;
            int token = m0 + row;
            if (token < M) {
                uint32x4 val = *(const uint32x4*)(Cs + row * 136 + cu * 8);
                if constexpr (OMODE == 1) {
                    int gc = n0 + cu * 8;
                    int which = gc >= 1536 ? 2 : (gc >= 768 ? 1 : 0);
                    int rem = gc - which * 768;
                    int h = rem >> 6, d = rem & 63;
                    int b = token / Nn, nn = token - b * Nn;
                    CT* dst = (which == 0 ? C : which == 1 ? C1 : C2);
                    __builtin_nontemporal_store(val,
                        (uint32x4*)(dst + (((long)(b * NH + h) * Nn + nn) << 6) + d));
                } else {
                    __builtin_nontemporal_store(val,
                        (uint32x4*)(C + (long)token * N + n0 + cu * 8));
                }
            }
        }
    } else {
#pragma unroll
        for (int i2 = 0; i2 < 4; ++i2)
#pragma unroll
            for (int j2 = 0; j2 < 4; ++j2) {
                int colc = n0 + wcc + j2 * 16 + lrow;
                float bv = HASB ? bias[colc] : 0.f;
#pragma unroll
                for (int q = 0; q < 4; ++q) {
                    int r = m0 + wrr + i2 * 16 + lgrp * 4 + q;
                    if (r < M) {
                        float v = acc[i2][j2][q] + bv;
                        if (HASR) v += res[(long)r * N + colc];
                        __builtin_nontemporal_store(v, &C[(long)r * N + colc]);
                    }
                }
            }
    }
}

// ---------------- fp32 tiled GEMM (tiny head GEMM only) ----------------
template <int HASB, int HASR>
__global__ __launch_bounds__(256) void k_gemm(
        const float* __restrict__ A, const float* __restrict__ Wt,
        const float* __restrict__ bias, const float* __restrict__ res,
        float* __restrict__ Co, int M, int Nc, int K) {
    __shared__ float As[16][65];
    __shared__ float Bs[16][68];
    int n0 = blockIdx.x * 64, m0 = blockIdx.y * 64;
    int tid = threadIdx.x;
    int tr = tid / 16, tc = tid % 16;
    int am = tid / 4, ak = (tid % 4) * 4;
    int bk = tid / 16, bn = (tid % 16) * 4;
    float acc[4][4] = {};
    bool nfull = (n0 + 64 <= Nc);
    for (int k0 = 0; k0 < K; k0 += 16) {
        float4 av = {0, 0, 0, 0};
        if (m0 + am < M) av = *(const float4*)&A[(long)(m0 + am) * K + k0 + ak];
        As[ak + 0][am] = av.x; As[ak + 1][am] = av.y;
        As[ak + 2][am] = av.z; As[ak + 3][am] = av.w;
        if (nfull) {
            float4 bv = *(const float4*)&Wt[(long)(k0 + bk) * Nc + n0 + bn];
            Bs[bk][bn + 0] = bv.x; Bs[bk][bn + 1] = bv.y;
            Bs[bk][bn + 2] = bv.z; Bs[bk][bn + 3] = bv.w;
        } else {
#pragma unroll
            for (int u = 0; u < 4; u++)
                Bs[bk][bn + u] = (n0 + bn + u < Nc) ? Wt[(long)(k0 + bk) * Nc + n0 + bn + u] : 0.f;
        }
        __syncthreads();
#pragma unroll
        for (int kk = 0; kk < 16; kk++) {
            float a0 = As[kk][tr * 4 + 0], a1 = As[kk][tr * 4 + 1];
            float a2 = As[kk][tr * 4 + 2], a3 = As[kk][tr * 4 + 3];
            float b0 = Bs[kk][tc], b1 = Bs[kk][tc + 16];
            float b2 = Bs[kk][tc + 32], b3 = Bs[kk][tc + 48];
            acc[0][0] += a0 * b0; acc[0][1] += a0 * b1; acc[0][2] += a0 * b2; acc[0][3] += a0 * b3;
            acc[1][0] += a1 * b0; acc[1][1] += a1 * b1; acc[1][2] += a1 * b2; acc[1][3] += a1 * b3;
            acc[2][0] += a2 * b0; acc[2][1] += a2 * b1; acc[2][2] += a2 * b2; acc[2][3] += a2 * b3;
            acc[3][0] += a3 * b0; acc[3][1] += a3 * b1; acc[3][2] += a3 * b2; acc[3][3] += a3 * b3;
        }
        __syncthreads();
    }
#pragma unroll
    for (int i = 0; i < 4; i++) {
        int r = m0 + tr * 4 + i;
        if (r >= M) continue;
#pragma unroll
        for (int j = 0; j < 4; j++) {
            int c0 = n0 + tc + j * 16;
            if (c0 >= Nc) continue;
            float v = acc[i][j];
            if (HASB) v += bias[c0];
            if (HASR) v += res[(long)r * Nc + c0];
            Co[(long)r * Nc + c0] = v;
        }
    }
}

// ---------------- scores: raw q.k -> f16 dots[b,h,i,j] ----------------
// sph & 0.125 scale skipped: positive per-(i,j) factor identical across heads
// cancels in the cross-head z-score (validated R3/R4).
// Head-major inputs: qh/kh [b,h,n,64].
__global__ __launch_bounds__(256) void k_scores16(
        const half_t* __restrict__ qh, const half_t* __restrict__ kh,
        half_t* __restrict__ dots) {
    const int bh = blockIdx.y;
    const int i0 = blockIdx.x * 16;
    __shared__ half_t qs[16][72], ks[16][72];
    const int tid = threadIdx.x;
    const int ti = tid >> 4, tj = tid & 15;
    const half_t* Qp = qh + (long)bh * Nn * 64;
    const half_t* Kp = kh + (long)bh * Nn * 64;
    if (tid < 128) {
        int sr = tid >> 3, sc = (tid & 7) * 8;
        int rq = i0 + sr; if (rq > Nn - 1) rq = Nn - 1;
        *(half8*)&qs[sr][sc] = *(const half8*)&Qp[(long)rq * 64 + sc];
    }
    for (int jt = 0; jt < 13; jt++) {
        __syncthreads();
        if (tid < 128) {
            int sr = tid >> 3, sc = (tid & 7) * 8;
            int rk = jt * 16 + sr; if (rk > Nn - 1) rk = Nn - 1;
            *(half8*)&ks[sr][sc] = *(const half8*)&Kp[(long)rk * 64 + sc];
        }
        __syncthreads();
        float acc = 0.f;
#pragma unroll
        for (int k = 0; k < 64; k += 8) {
            half8 qv = *(const half8*)&qs[ti][k];
            half8 kv = *(const half8*)&ks[tj][k];
#pragma unroll
            for (int u = 0; u < 8; u++) acc += (float)qv[u] * (float)kv[u];
        }
        int i = i0 + ti, j = jt * 16 + tj;
        if (i < Nn && j < Nn)
            dots[((long)bh * Nn + i) * Nn + j] = (half_t)acc;
    }
}

// ---------------- cross-head z-score (ddof=1), f16 in-place ----------------
__global__ __launch_bounds__(256) void k_hn16(half_t* __restrict__ dots) {
    const int i = blockIdx.x, b = blockIdx.y;
    const int j = threadIdx.x;
    if (j >= Nn) return;
    const long hs = (long)Nn * Nn;
    long base = ((long)(b * NH) * Nn + i) * Nn + j;
    float v[NH];
    float mu = 0.f;
#pragma unroll
    for (int h = 0; h < NH; h++) { v[h] = (float)dots[base + h * hs]; mu += v[h]; }
    mu *= (1.f / NH);
    float s2 = 0.f;
#pragma unroll
    for (int h = 0; h < NH; h++) { float d = v[h] - mu; s2 += d * d; }
    float rs = rsqrtf(s2 * (1.f / (NH - 1)));
#pragma unroll
    for (int h = 0; h < NH; h++) dots[base + h * hs] = (half_t)((v[h] - mu) * rs);
}

// ---------------- fused row softmax + attn@V (head-major V) ----------------
__global__ __launch_bounds__(256) void k_sm_av(
        const half_t* __restrict__ dots, const half_t* __restrict__ vh,
        half_t* __restrict__ o) {
    const int bh = blockIdx.y;
    const int b = bh / NH, h = bh % NH;
    const int i0 = blockIdx.x * 16;
    __shared__ float P[16][208];
    __shared__ half_t vs[16][72];
    __shared__ float invr[16];
    const int tid = threadIdx.x;
    const int r = tid >> 4, c0 = tid & 15;

    int ri = i0 + r; if (ri > Nn - 1) ri = Nn - 1;
    const half_t* dp = dots + ((long)bh * Nn + ri) * Nn;
    float vbuf[13];
    float mx = -1e30f;
#pragma unroll
    for (int t = 0; t < 13; t++) {
        int j = c0 + t * 16;
        float v = (j < Nn) ? (float)dp[j] : -1e30f;
        vbuf[t] = v;
        mx = fmaxf(mx, v);
    }
    mx = fmaxf(mx, __shfl_xor(mx, 1));
    mx = fmaxf(mx, __shfl_xor(mx, 2));
    mx = fmaxf(mx, __shfl_xor(mx, 4));
    mx = fmaxf(mx, __shfl_xor(mx, 8));
    float sum = 0.f;
#pragma unroll
    for (int t = 0; t < 13; t++) {
        int j = c0 + t * 16;
        float v = (j < Nn) ? __expf(vbuf[t] - mx) : 0.f;
        P[r][j] = v;
        sum += v;
    }
    sum += __shfl_xor(sum, 1);
    sum += __shfl_xor(sum, 2);
    sum += __shfl_xor(sum, 4);
    sum += __shfl_xor(sum, 8);
    if (c0 == 0) invr[r] = 1.f / sum;
    __syncthreads();

    const int ti = tid >> 4, td = tid & 15;
    float acc[4] = {0, 0, 0, 0};
    const int vr = tid >> 3, vc = (tid & 7) * 8;
    const half_t* Vp = vh + (long)bh * Nn * 64;
    for (int jt = 0; jt < 13; jt++) {
        if (tid < 128) {
            int rv = jt * 16 + vr; if (rv > Nn - 1) rv = Nn - 1;
            *(half8*)&vs[vr][vc] = *(const half8*)&Vp[(long)rv * 64 + vc];
        }
        __syncthreads();
#pragma unroll
        for (int jj = 0; jj < 16; jj++) {
            float av = P[ti][jt * 16 + jj];
#pragma unroll
            for (int t = 0; t < 4; t++) acc[t] += av * (float)vs[jj][td + t * 16];
        }
        __syncthreads();
    }
    if (i0 + ti < Nn) {
        float inv = invr[ti];
        half_t* op = o + ((long)(b * Nn + i0 + ti)) * INNERc + h * 64;
#pragma unroll
        for (int t = 0; t < 4; t++) op[td + t * 16] = (half_t)(acc[t] * inv);
    }
}

// ---------------- host launcher ----------------
extern "C" void kernel_launch(void* const* d_in, const int* in_sizes, int n_in,
                              void* d_out, int out_size, void* d_ws, size_t ws_size,
                              hipStream_t stream) {
    const float* img     = (const float*)d_in[0];
    const float* patch_g = (const float*)d_in[2];
    const float* patch_b = (const float*)d_in[3];
    const float* W_patch = (const float*)d_in[4];
    const float* b_patch = (const float*)d_in[5];
    const float* emb_g   = (const float*)d_in[6];
    const float* emb_b   = (const float*)d_in[7];
    const float* pos     = (const float*)d_in[8];
    const float* cls     = (const float*)d_in[9];
    const float* ln_g    = (const float*)d_in[10];
    const float* ln_b    = (const float*)d_in[11];
    const float* W_qkv   = (const float*)d_in[12];
    const float* W_out   = (const float*)d_in[13];
    const float* b_out   = (const float*)d_in[14];
    const float* fin_g   = (const float*)d_in[15];
    const float* fin_b   = (const float*)d_in[16];
    const float* W_head  = (const float*)d_in[17];
    const float* b_head  = (const float*)d_in[18];
    float* out = (float*)d_out;

    const long SZ_XD   = (long)Bc * Nn * Dd;          // 4,841,472
    const long SZ_HD   = (long)Bc * NH * Nn * DHd;    // 4,841,472
    const long SZ_DOTS = (long)Bc * NH * Nn * Nn;     // 14,902,656
    const long SZ_TMP  = (long)Bc * NPc * Dd;

    float* x    = (float*)d_ws;
    float* tmp  = x + SZ_XD;
    float* clsb = tmp + SZ_TMP;
    half_t* xh       = (half_t*)(clsb + 32 * 768);
    half_t* qhb      = xh + SZ_XD;
    half_t* khb      = qhb + SZ_HD;
    half_t* vhb      = khb + SZ_HD;
    half_t* dotsh    = vhb + SZ_HD;
    half_t* wt_patch = dotsh + SZ_DOTS;
    half_t* wt_qkv   = wt_patch + (long)Dd * Dd;
    half_t* wt_out   = wt_qkv + (long)DEPTHc * 3 * INNERc * Dd;

    // ---- weight prep: fp32 [K][N] -> f16 [N][K] ----
    hipLaunchKernelGGL(k_wprep, dim3(Dd / 32, Dd / 32, 1), dim3(32, 8), 0, stream,
                       W_patch, wt_patch, Dd, Dd);
    hipLaunchKernelGGL(k_wprep, dim3(3 * INNERc / 32, Dd / 32, DEPTHc), dim3(32, 8), 0, stream,
                       W_qkv, wt_qkv, Dd, 3 * INNERc);
    hipLaunchKernelGGL(k_wprep, dim3(Dd / 32, Dd / 32, DEPTHc), dim3(32, 8), 0, stream,
                       W_out, wt_out, Dd, Dd);

    // 1. patchify + patch LN -> xh (f16)
    hipLaunchKernelGGL(k_patch_ln, dim3(Bc * NPc), dim3(256), 0, stream,
                       img, patch_g, patch_b, xh);
    // 2. patch GEMM (+b_patch) -> tmp fp32
    hipLaunchKernelGGL((k_hgemm<1, 0, float, 0>), dim3(6 * 49), dim3(256), 0, stream,
                       xh, wt_patch, b_patch, nullptr, tmp, nullptr, nullptr,
                       Bc * NPc, Dd, Dd);
    // 3. emb LN + cls concat + pos add -> x
    hipLaunchKernelGGL(k_embed, dim3(Bc * Nn), dim3(256), 0, stream,
                       tmp, cls, pos, emb_g, emb_b, x);

    const int Mrows = Bc * Nn;  // 6304
    for (int l = 0; l < DEPTHc; l++) {
        const float* g  = ln_g + (long)l * Dd;
        const float* bb = ln_b + (long)l * Dd;
        const half_t* Wq = wt_qkv + (long)l * 3 * INNERc * Dd;
        const half_t* Wo = wt_out + (long)l * Dd * Dd;
        const float* bo = b_out + (long)l * Dd;
        hipLaunchKernelGGL((k_ln<half_t>), dim3(Mrows), dim3(256), 0, stream,
                           x, g, bb, xh, (long)Dd, (long)Dd);
        hipLaunchKernelGGL((k_hgemm<0, 0, half_t, 1>), dim3(18 * 50), dim3(256), 0, stream,
                           xh, Wq, nullptr, nullptr, qhb, khb, vhb,
                           Mrows, 3 * INNERc, Dd);
        hipLaunchKernelGGL(k_scores16, dim3(13, Bc * NH), dim3(256), 0, stream,
                           qhb, khb, dotsh);
        hipLaunchKernelGGL(k_hn16, dim3(Nn, Bc), dim3(256), 0, stream,
                           dotsh);
        hipLaunchKernelGGL(k_sm_av, dim3(13, Bc * NH), dim3(256), 0, stream,
                           dotsh, vhb, xh);
        hipLaunchKernelGGL((k_hgemm<1, 1, float, 0>), dim3(6 * 50), dim3(256), 0, stream,
                           xh, Wo, bo, x, x, nullptr, nullptr,
                           Mrows, Dd, Dd);
    }
    // final LN (cls rows only) -> clsb fp32
    hipLaunchKernelGGL((k_ln<float>), dim3(Bc), dim3(256), 0, stream,
                       x, fin_g, fin_b, clsb, (long)Nn * Dd, (long)Dd);
    // head GEMM (fp32, tiny)
    hipLaunchKernelGGL((k_gemm<1, 0>), dim3(16, 1), dim3(256), 0, stream,
                       clsb, W_head, b_head, nullptr, out, Bc, NCLS, Dd);
}

// Round 6
// 2532.634 us; speedup vs baseline: 3.9897x; 1.1172x over previous
//
#include <hip/hip_runtime.h>
#include <math.h>

// ---------------- problem constants ----------------
constexpr int Bc = 32, Cch = 3, Hh = 224, Ww = 224, Pp = 16;
constexpr int Dd = 768, NH = 12, DHd = 64, INNERc = 768;
constexpr int DEPTHc = 12, NCLS = 1000;
constexpr int NPc = 196, Nn = 197, PD = 768;
constexpr float EPSf = 1e-5f;

typedef _Float16 half_t;
typedef __attribute__((ext_vector_type(8))) _Float16 half8;
typedef __attribute__((ext_vector_type(4))) float f32x4;
typedef __attribute__((ext_vector_type(4))) unsigned int uint32x4;

// ---------------- reduction helpers ----------------
__device__ __forceinline__ float wave_red_sum(float v) {
#pragma unroll
    for (int m = 32; m; m >>= 1) v += __shfl_xor(v, m);
    return v;
}

__device__ __forceinline__ void block_red2(float& s, float& s2, float* red) {
    s = wave_red_sum(s);
    s2 = wave_red_sum(s2);
    int wid = threadIdx.x >> 6, lane = threadIdx.x & 63;
    if (lane == 0) { red[wid] = s; red[4 + wid] = s2; }
    __syncthreads();
    s = red[0] + red[1] + red[2] + red[3];
    s2 = red[4] + red[5] + red[6] + red[7];
}

// ---------------- patchify + patch LN -> f16 ----------------
__global__ __launch_bounds__(256) void k_patch_ln(
        const float* __restrict__ img, const float* __restrict__ g,
        const float* __restrict__ bb, half_t* __restrict__ out) {
    int pid = blockIdx.x;
    int b = pid / NPc, n = pid % NPc;
    int ph = n / 14, pw = n % 14;
    int t = threadIdx.x;
    __shared__ float red[8];
    float v[3];
#pragma unroll
    for (int i = 0; i < 3; i++) {
        int d = t + i * 256;
        int c = d % 3, q = (d / 3) & 15, p = d / 48;
        v[i] = img[((long)(b * Cch + c) * Hh + ph * Pp + p) * Ww + pw * Pp + q];
    }
    float s = v[0] + v[1] + v[2];
    float s2 = v[0] * v[0] + v[1] * v[1] + v[2] * v[2];
    block_red2(s, s2, red);
    float mu = s * (1.f / PD);
    float var = s2 * (1.f / PD) - mu * mu;
    float r = rsqrtf(var + EPSf);
#pragma unroll
    for (int i = 0; i < 3; i++) {
        int d = t + i * 256;
        out[(long)pid * PD + d] = (half_t)((v[i] - mu) * r * g[d] + bb[d]);
    }
}

// ---------------- row LayerNorm (768 wide), templated output ----------------
template <typename T>
__global__ __launch_bounds__(256) void k_ln(
        const float* __restrict__ in, const float* __restrict__ g,
        const float* __restrict__ bb, T* __restrict__ out,
        long in_stride, long out_stride) {
    long row = blockIdx.x;
    const float* ip = in + row * in_stride;
    T* op = out + row * out_stride;
    int t = threadIdx.x;
    __shared__ float red[8];
    float v[3];
#pragma unroll
    for (int i = 0; i < 3; i++) v[i] = ip[t + i * 256];
    float s = v[0] + v[1] + v[2];
    float s2 = v[0] * v[0] + v[1] * v[1] + v[2] * v[2];
    block_red2(s, s2, red);
    float mu = s * (1.f / Dd);
    float var = s2 * (1.f / Dd) - mu * mu;
    float r = rsqrtf(var + EPSf);
#pragma unroll
    for (int i = 0; i < 3; i++) {
        int d = t + i * 256;
        op[d] = (T)((v[i] - mu) * r * g[d] + bb[d]);
    }
}

// ---------------- embed assemble: LN(tmp)+pos, cls+pos ----------------
__global__ __launch_bounds__(256) void k_embed(
        const float* __restrict__ tmp, const float* __restrict__ cls,
        const float* __restrict__ pos, const float* __restrict__ g,
        const float* __restrict__ bb, float* __restrict__ x) {
    int pid = blockIdx.x;
    int b = pid / Nn, n = pid % Nn;
    int t = threadIdx.x;
    float* xp = x + (long)pid * Dd;
    if (n == 0) {
#pragma unroll
        for (int i = 0; i < 3; i++) {
            int d = t + i * 256;
            xp[d] = cls[d] + pos[d];
        }
        return;
    }
    const float* ip = tmp + (long)(b * NPc + n - 1) * Dd;
    __shared__ float red[8];
    float v[3];
#pragma unroll
    for (int i = 0; i < 3; i++) v[i] = ip[t + i * 256];
    float s = v[0] + v[1] + v[2];
    float s2 = v[0] * v[0] + v[1] * v[1] + v[2] * v[2];
    block_red2(s, s2, red);
    float mu = s * (1.f / Dd);
    float var = s2 * (1.f / Dd) - mu * mu;
    float r = rsqrtf(var + EPSf);
#pragma unroll
    for (int i = 0; i < 3; i++) {
        int d = t + i * 256;
        xp[d] = (v[i] - mu) * r * g[d] + bb[d] + pos[(long)n * Dd + d];
    }
}

// ---------------- weight prep: fp32 W[K][N] -> f16 Wt[N][K] ----------------
__global__ __launch_bounds__(256) void k_wprep(
        const float* __restrict__ W, half_t* __restrict__ Wt, int K, int N) {
    W += (long)blockIdx.z * K * N;
    Wt += (long)blockIdx.z * K * N;
    __shared__ float tile[32][33];
    int n = blockIdx.x * 32 + threadIdx.x;
    int k0 = blockIdx.y * 32;
#pragma unroll
    for (int i = 0; i < 4; i++)
        tile[threadIdx.y + i * 8][threadIdx.x] = W[(long)(k0 + threadIdx.y + i * 8) * N + n];
    __syncthreads();
    int kk = k0 + threadIdx.x;
#pragma unroll
    for (int i = 0; i < 4; i++)
        Wt[(long)(blockIdx.x * 32 + threadIdx.y + i * 8) * K + kk] =
            (half_t)tile[threadIdx.x][threadIdx.y + i * 8];
}

// ---------------- f16 MFMA GEMM ----------------
__device__ __forceinline__ half8 lds_frag(const uint32x4 (*L)[8], int row, int slot) {
    union { uint32x4 u; half8 h; } t;
    t.u = L[row][slot];
    return t.h;
}

template <int HASB, int HASR, typename CT, int OMODE>
__global__ __launch_bounds__(256, 2) void k_hgemm(
        const half_t* __restrict__ A, const half_t* __restrict__ Bt,
        const float* __restrict__ bias, const float* __restrict__ res,
        CT* __restrict__ C, CT* __restrict__ C1, CT* __restrict__ C2,
        int M, int N, int K) {
    __shared__ uint32x4 smem[2176];
    uint32x4 (*As)[8] = (uint32x4(*)[8])smem;
    uint32x4 (*Bs)[8] = (uint32x4(*)[8])(smem + 1024);
    const int tid = threadIdx.x;
    const int nwg = gridDim.x;
    const int q8 = nwg >> 3, r8 = nwg & 7;
    const int xc = blockIdx.x & 7, oo = blockIdx.x >> 3;
    const int tile = (xc < r8 ? xc * (q8 + 1) : r8 * (q8 + 1) + (xc - r8) * q8) + oo;
    const int gx = N >> 7;
    const int n0 = (tile % gx) * 128, m0 = (tile / gx) * 128;
    const int lane = tid & 63, w = tid >> 6;
    const int wrr = (w >> 1) * 64, wcc = (w & 1) * 64;
    const int lrow = lane & 15, lgrp = lane >> 4;

    int lm[4], sw[4];
    long gA[4], gB[4];
    const int cb = (tid & 7) * 8;
#pragma unroll
    for (int c = 0; c < 4; ++c) {
        lm[c] = c * 32 + (tid >> 3);
        sw[c] = (tid & 7) ^ (lm[c] & 7);
        int ma = m0 + lm[c];
        if (ma > M - 1) ma = M - 1;
        gA[c] = (long)ma * K + cb;
        gB[c] = (long)(n0 + lm[c]) * K + cb;
    }

    f32x4 acc[4][4] = {};
    uint32x4 ra[4], rb[4];
#pragma unroll
    for (int c = 0; c < 4; ++c) { ra[c] = *(const uint32x4*)(A + gA[c]); rb[c] = *(const uint32x4*)(Bt + gB[c]); }
#pragma unroll
    for (int c = 0; c < 4; ++c) { As[lm[c]][sw[c]] = ra[c]; Bs[lm[c]][sw[c]] = rb[c]; }
    __syncthreads();

    const int nst = K >> 6;
    for (int t = 0; t < nst; ++t) {
        if (t + 1 < nst) {
            const int k0 = (t + 1) << 6;
#pragma unroll
            for (int c = 0; c < 4; ++c) {
                ra[c] = *(const uint32x4*)(A + gA[c] + k0);
                rb[c] = *(const uint32x4*)(Bt + gB[c] + k0);
            }
        }
#pragma unroll
        for (int kh = 0; kh < 2; ++kh) {
            half8 af[4], bf[4];
#pragma unroll
            for (int i2 = 0; i2 < 4; ++i2) {
                int m = wrr + i2 * 16 + lrow;
                af[i2] = lds_frag(As, m, (kh * 4 + lgrp) ^ (m & 7));
                int n = wcc + i2 * 16 + lrow;
                bf[i2] = lds_frag(Bs, n, (kh * 4 + lgrp) ^ (n & 7));
            }
#pragma unroll
            for (int i2 = 0; i2 < 4; ++i2)
#pragma unroll
                for (int j2 = 0; j2 < 4; ++j2)
                    acc[i2][j2] = __builtin_amdgcn_mfma_f32_16x16x32_f16(af[i2], bf[j2], acc[i2][j2], 0, 0, 0);
        }
        if (t + 1 < nst) {
            __syncthreads();
#pragma unroll
            for (int c = 0; c < 4; ++c) { As[lm[c]][sw[c]] = ra[c]; Bs[lm[c]][sw[c]] = rb[c]; }
            __syncthreads();
        }
    }

    if constexpr (sizeof(CT) == 2) {
        __syncthreads();
        half_t* Cs = (half_t*)smem;
#pragma unroll
        for (int i2 = 0; i2 < 4; ++i2)
#pragma unroll
            for (int j2 = 0; j2 < 4; ++j2) {
                int colc = wcc + j2 * 16 + lrow;
                float bv = HASB ? bias[n0 + colc] : 0.f;
#pragma unroll
                for (int q = 0; q < 4; ++q) {
                    int r = wrr + i2 * 16 + lgrp * 4 + q;
                    Cs[r * 136 + colc] = (half_t)(acc[i2][j2][q] + bv);
                }
            }
        __syncthreads();
#pragma unroll
        for (int it = 0; it < 8; ++it) {
            int idx = tid + it * 256;
            int row = idx >> 4, cu = idx & 15;
            int token = m0 + row;
            if (token < M) {
                uint32x4 val = *(const uint32x4*)(Cs + row * 136 + cu * 8);
                if constexpr (OMODE == 1) {
                    int gc = n0 + cu * 8;
                    int which = gc >= 1536 ? 2 : (gc >= 768 ? 1 : 0);
                    int rem = gc - which * 768;
                    int h = rem >> 6, d = rem & 63;
                    int b = token / Nn, nn = token - b * Nn;
                    CT* dst = (which == 0 ? C : which == 1 ? C1 : C2);
                    __builtin_nontemporal_store(val,
                        (uint32x4*)(dst + (((long)(b * NH + h) * Nn + nn) << 6) + d));
                } else {
                    __builtin_nontemporal_store(val,
                        (uint32x4*)(C + (long)token * N + n0 + cu * 8));
                }
            }
        }
    } else {
#pragma unroll
        for (int i2 = 0; i2 < 4; ++i2)
#pragma unroll
            for (int j2 = 0; j2 < 4; ++j2) {
                int colc = n0 + wcc + j2 * 16 + lrow;
                float bv = HASB ? bias[colc] : 0.f;
#pragma unroll
                for (int q = 0; q < 4; ++q) {
                    int r = m0 + wrr + i2 * 16 + lgrp * 4 + q;
                    if (r < M) {
                        float v = acc[i2][j2][q] + bv;
                        if (HASR) v += res[(long)r * N + colc];
                        __builtin_nontemporal_store(v, &C[(long)r * N + colc]);
                    }
                }
            }
    }
}

// ---------------- fp32 tiled GEMM (tiny head GEMM only) ----------------
template <int HASB, int HASR>
__global__ __launch_bounds__(256) void k_gemm(
        const float* __restrict__ A, const float* __restrict__ Wt,
        const float* __restrict__ bias, const float* __restrict__ res,
        float* __restrict__ Co, int M, int Nc, int K) {
    __shared__ float As[16][65];
    __shared__ float Bs[16][68];
    int n0 = blockIdx.x * 64, m0 = blockIdx.y * 64;
    int tid = threadIdx.x;
    int tr = tid / 16, tc = tid % 16;
    int am = tid / 4, ak = (tid % 4) * 4;
    int bk = tid / 16, bn = (tid % 16) * 4;
    float acc[4][4] = {};
    bool nfull = (n0 + 64 <= Nc);
    for (int k0 = 0; k0 < K; k0 += 16) {
        float4 av = {0, 0, 0, 0};
        if (m0 + am < M) av = *(const float4*)&A[(long)(m0 + am) * K + k0 + ak];
        As[ak + 0][am] = av.x; As[ak + 1][am] = av.y;
        As[ak + 2][am] = av.z; As[ak + 3][am] = av.w;
        if (nfull) {
            float4 bv = *(const float4*)&Wt[(long)(k0 + bk) * Nc + n0 + bn];
            Bs[bk][bn + 0] = bv.x; Bs[bk][bn + 1] = bv.y;
            Bs[bk][bn + 2] = bv.z; Bs[bk][bn + 3] = bv.w;
        } else {
#pragma unroll
            for (int u = 0; u < 4; u++)
                Bs[bk][bn + u] = (n0 + bn + u < Nc) ? Wt[(long)(k0 + bk) * Nc + n0 + bn + u] : 0.f;
        }
        __syncthreads();
#pragma unroll
        for (int kk = 0; kk < 16; kk++) {
            float a0 = As[kk][tr * 4 + 0], a1 = As[kk][tr * 4 + 1];
            float a2 = As[kk][tr * 4 + 2], a3 = As[kk][tr * 4 + 3];
            float b0 = Bs[kk][tc], b1 = Bs[kk][tc + 16];
            float b2 = Bs[kk][tc + 32], b3 = Bs[kk][tc + 48];
            acc[0][0] += a0 * b0; acc[0][1] += a0 * b1; acc[0][2] += a0 * b2; acc[0][3] += a0 * b3;
            acc[1][0] += a1 * b0; acc[1][1] += a1 * b1; acc[1][2] += a1 * b2; acc[1][3] += a1 * b3;
            acc[2][0] += a2 * b0; acc[2][1] += a2 * b1; acc[2][2] += a2 * b2; acc[2][3] += a2 * b3;
            acc[3][0] += a3 * b0; acc[3][1] += a3 * b1; acc[3][2] += a3 * b2; acc[3][3] += a3 * b3;
        }
        __syncthreads();
    }
#pragma unroll
    for (int i = 0; i < 4; i++) {
        int r = m0 + tr * 4 + i;
        if (r >= M) continue;
#pragma unroll
        for (int j = 0; j < 4; j++) {
            int c0 = n0 + tc + j * 16;
            if (c0 >= Nc) continue;
            float v = acc[i][j];
            if (HASB) v += bias[c0];
            if (HASR) v += res[(long)r * Nc + c0];
            Co[(long)r * Nc + c0] = v;
        }
    }
}

// ---------------- V transpose: [b,h,n,64] -> [b,h,64,224] (n zero-padded) ----------------
__global__ __launch_bounds__(256) void k_vtrans(
        const half_t* __restrict__ vh, half_t* __restrict__ vt) {
    const int bh = blockIdx.x;
    __shared__ half_t vsT[Nn][68];
    const int tid = threadIdx.x;
    const half_t* Vp = vh + (long)bh * Nn * 64;
    for (int idx = tid; idx < Nn * 8; idx += 256) {
        int r = idx >> 3, c8 = (idx & 7) * 8;
        *(half8*)&vsT[r][c8] = *(const half8*)&Vp[(long)r * 64 + c8];
    }
    __syncthreads();
    half_t* Tp = vt + (long)bh * 64 * 224;
    for (int idx = tid; idx < 64 * 112; idx += 256) {
        int d = idx / 112, p = idx % 112;
        int n0 = p * 2;
        union { unsigned int u; half_t h[2]; } t;
        t.h[0] = (n0 < Nn) ? vsT[n0][d] : (half_t)0.f;
        t.h[1] = (n0 + 1 < Nn) ? vsT[n0 + 1][d] : (half_t)0.f;
        *(unsigned int*)&Tp[(long)d * 224 + n0] = t.u;
    }
}

// ---------------- fused attention: QK^T + cross-head z-score + softmax + PV ----------------
// Block per (b, i-tile16): all 12 heads in-block (hn is block-local).
// Pass1: MFMA S, accumulate sum/sumsq in regs -> LDS atomics.
// Pass2: recompute S (deterministic), z-score, wave softmax, P->LDS, PV MFMA.
// Frags loaded straight from global (head-major => contiguous 8-half k-slices).
__global__ __launch_bounds__(256) void k_attn(
        const half_t* __restrict__ qh, const half_t* __restrict__ kh,
        const half_t* __restrict__ vt, half_t* __restrict__ o) {
    __shared__ float muB[16][212];      // sum -> mu
    __shared__ float rsB[16][212];      // sumsq -> rsqrt(var)
    __shared__ half_t PB[4][16][232];   // per-wave P tiles
    const int tid = threadIdx.x;
    // bijective XCD swizzle: nwg=416 = 8*52, 13 i-tiles/b, 52 = 4 b's per XCD chunk
    const int tile = (blockIdx.x & 7) * 52 + (blockIdx.x >> 3);
    const int b = tile / 13, it = tile % 13;
    const int i0 = it * 16;
    const int w = tid >> 6, lane = tid & 63;
    const int lrow = lane & 15, lg = lane >> 4;

    for (int idx = tid; idx < 16 * 212; idx += 256) {
        ((float*)muB)[idx] = 0.f;
        ((float*)rsB)[idx] = 0.f;
    }
    // zero PB pad cols 208..231 (never rewritten)
    for (int idx = tid; idx < 768; idx += 256) {
        int ww = idx / 192, rr = (idx % 192) / 12, u = idx % 12;
        *(unsigned int*)&PB[ww][rr][208 + u * 2] = 0u;
    }
    __syncthreads();

    int arow = i0 + lrow; if (arow > Nn - 1) arow = Nn - 1;
    const int hbase = b * NH;

    // ---- pass 1: sums ----
    float sv[13][4] = {};
    float sq[13][4] = {};
#pragma unroll
    for (int hh = 0; hh < 3; hh++) {
        int h = w * 3 + hh;
        const half_t* Qp = qh + ((long)(hbase + h) * Nn) * 64;
        const half_t* Kp = kh + ((long)(hbase + h) * Nn) * 64;
        half8 af0 = *(const half8*)&Qp[(long)arow * 64 + lg * 8];
        half8 af1 = *(const half8*)&Qp[(long)arow * 64 + 32 + lg * 8];
#pragma unroll
        for (int jt = 0; jt < 13; jt++) {
            int jr = jt * 16 + lrow; if (jr > Nn - 1) jr = Nn - 1;
            half8 bf0 = *(const half8*)&Kp[(long)jr * 64 + lg * 8];
            half8 bf1 = *(const half8*)&Kp[(long)jr * 64 + 32 + lg * 8];
            f32x4 acc = {};
            acc = __builtin_amdgcn_mfma_f32_16x16x32_f16(af0, bf0, acc, 0, 0, 0);
            acc = __builtin_amdgcn_mfma_f32_16x16x32_f16(af1, bf1, acc, 0, 0, 0);
#pragma unroll
            for (int q = 0; q < 4; q++) {
                float s = acc[q];
                sv[jt][q] += s;
                sq[jt][q] += s * s;
            }
        }
    }
#pragma unroll
    for (int jt = 0; jt < 13; jt++)
#pragma unroll
        for (int q = 0; q < 4; q++) {
            int r = lg * 4 + q, j = jt * 16 + lrow;
            atomicAdd(&muB[r][j], sv[jt][q]);
            atomicAdd(&rsB[r][j], sq[jt][q]);
        }
    __syncthreads();
    for (int idx = tid; idx < 16 * 212; idx += 256) {
        float s = ((float*)muB)[idx], s2 = ((float*)rsB)[idx];
        float mu = s * (1.f / NH);
        float var = (s2 - s * mu) * (1.f / (NH - 1));
        ((float*)muB)[idx] = mu;
        ((float*)rsB)[idx] = rsqrtf(var);
    }
    __syncthreads();

    // ---- pass 2: z-score + softmax + PV ----
#pragma unroll 1
    for (int hh = 0; hh < 3; hh++) {
        int h = w * 3 + hh;
        const half_t* Qp = qh + ((long)(hbase + h) * Nn) * 64;
        const half_t* Kp = kh + ((long)(hbase + h) * Nn) * 64;
        half8 af0 = *(const half8*)&Qp[(long)arow * 64 + lg * 8];
        half8 af1 = *(const half8*)&Qp[(long)arow * 64 + 32 + lg * 8];
        float ez[13][4];
        float mx[4] = {-1e30f, -1e30f, -1e30f, -1e30f};
#pragma unroll
        for (int jt = 0; jt < 13; jt++) {
            int jr = jt * 16 + lrow; if (jr > Nn - 1) jr = Nn - 1;
            half8 bf0 = *(const half8*)&Kp[(long)jr * 64 + lg * 8];
            half8 bf1 = *(const half8*)&Kp[(long)jr * 64 + 32 + lg * 8];
            f32x4 acc = {};
            acc = __builtin_amdgcn_mfma_f32_16x16x32_f16(af0, bf0, acc, 0, 0, 0);
            acc = __builtin_amdgcn_mfma_f32_16x16x32_f16(af1, bf1, acc, 0, 0, 0);
            int j = jt * 16 + lrow;
#pragma unroll
            for (int q = 0; q < 4; q++) {
                int r = lg * 4 + q;
                float z = (acc[q] - muB[r][j]) * rsB[r][j];
                if (j > Nn - 1) z = -1e30f;
                ez[jt][q] = z;
                mx[q] = fmaxf(mx[q], z);
            }
        }
#pragma unroll
        for (int st = 1; st <= 8; st <<= 1)
#pragma unroll
            for (int q = 0; q < 4; q++) mx[q] = fmaxf(mx[q], __shfl_xor(mx[q], st));
        float sm[4] = {0.f, 0.f, 0.f, 0.f};
#pragma unroll
        for (int jt = 0; jt < 13; jt++)
#pragma unroll
            for (int q = 0; q < 4; q++) {
                float e = __expf(ez[jt][q] - mx[q]);
                ez[jt][q] = e;
                sm[q] += e;
            }
#pragma unroll
        for (int st = 1; st <= 8; st <<= 1)
#pragma unroll
            for (int q = 0; q < 4; q++) sm[q] += __shfl_xor(sm[q], st);
        float inv[4];
#pragma unroll
        for (int q = 0; q < 4; q++) inv[q] = 1.f / sm[q];
#pragma unroll
        for (int jt = 0; jt < 13; jt++)
#pragma unroll
            for (int q = 0; q < 4; q++)
                PB[w][lg * 4 + q][jt * 16 + lrow] = (half_t)(ez[jt][q] * inv[q]);
        __syncthreads();   // uniform: all waves run 3 iterations

        const half_t* Vtp = vt + ((long)(hbase + h) * 64) * 224;
#pragma unroll
        for (int dt = 0; dt < 4; dt++) {
            f32x4 oacc = {};
#pragma unroll
            for (int kt = 0; kt < 7; kt++) {
                half8 pa = *(const half8*)&PB[w][lrow][kt * 32 + lg * 8];
                half8 vb = *(const half8*)&Vtp[(long)(dt * 16 + lrow) * 224 + kt * 32 + lg * 8];
                oacc = __builtin_amdgcn_mfma_f32_16x16x32_f16(pa, vb, oacc, 0, 0, 0);
            }
#pragma unroll
            for (int q = 0; q < 4; q++) {
                int i = i0 + lg * 4 + q;
                if (i < Nn)
                    o[((long)(b * Nn) + i) * INNERc + h * 64 + dt * 16 + lrow] = (half_t)oacc[q];
            }
        }
        __syncthreads();   // protect PB before next head overwrites
    }
}

// ---------------- host launcher ----------------
extern "C" void kernel_launch(void* const* d_in, const int* in_sizes, int n_in,
                              void* d_out, int out_size, void* d_ws, size_t ws_size,
                              hipStream_t stream) {
    const float* img     = (const float*)d_in[0];
    const float* patch_g = (const float*)d_in[2];
    const float* patch_b = (const float*)d_in[3];
    const float* W_patch = (const float*)d_in[4];
    const float* b_patch = (const float*)d_in[5];
    const float* emb_g   = (const float*)d_in[6];
    const float* emb_b   = (const float*)d_in[7];
    const float* pos     = (const float*)d_in[8];
    const float* cls     = (const float*)d_in[9];
    const float* ln_g    = (const float*)d_in[10];
    const float* ln_b    = (const float*)d_in[11];
    const float* W_qkv   = (const float*)d_in[12];
    const float* W_out   = (const float*)d_in[13];
    const float* b_out   = (const float*)d_in[14];
    const float* fin_g   = (const float*)d_in[15];
    const float* fin_b   = (const float*)d_in[16];
    const float* W_head  = (const float*)d_in[17];
    const float* b_head  = (const float*)d_in[18];
    float* out = (float*)d_out;

    const long SZ_XD  = (long)Bc * Nn * Dd;          // 4,841,472
    const long SZ_HD  = (long)Bc * NH * Nn * DHd;    // 4,841,472
    const long SZ_VT  = (long)Bc * NH * 64 * 224;    // 11,010,048 halves... (32*12*64*224)
    const long SZ_TMP = (long)Bc * NPc * Dd;

    float* x    = (float*)d_ws;
    float* tmp  = x + SZ_XD;
    float* clsb = tmp + SZ_TMP;
    half_t* xh       = (half_t*)(clsb + 32 * 768);
    half_t* qhb      = xh + SZ_XD;
    half_t* khb      = qhb + SZ_HD;
    half_t* vhb      = khb + SZ_HD;
    half_t* vtb      = vhb + SZ_HD;
    half_t* wt_patch = vtb + SZ_VT;
    half_t* wt_qkv   = wt_patch + (long)Dd * Dd;
    half_t* wt_out   = wt_qkv + (long)DEPTHc * 3 * INNERc * Dd;

    // ---- weight prep: fp32 [K][N] -> f16 [N][K] ----
    hipLaunchKernelGGL(k_wprep, dim3(Dd / 32, Dd / 32, 1), dim3(32, 8), 0, stream,
                       W_patch, wt_patch, Dd, Dd);
    hipLaunchKernelGGL(k_wprep, dim3(3 * INNERc / 32, Dd / 32, DEPTHc), dim3(32, 8), 0, stream,
                       W_qkv, wt_qkv, Dd, 3 * INNERc);
    hipLaunchKernelGGL(k_wprep, dim3(Dd / 32, Dd / 32, DEPTHc), dim3(32, 8), 0, stream,
                       W_out, wt_out, Dd, Dd);

    // 1. patchify + patch LN -> xh (f16)
    hipLaunchKernelGGL(k_patch_ln, dim3(Bc * NPc), dim3(256), 0, stream,
                       img, patch_g, patch_b, xh);
    // 2. patch GEMM (+b_patch) -> tmp fp32
    hipLaunchKernelGGL((k_hgemm<1, 0, float, 0>), dim3(6 * 49), dim3(256), 0, stream,
                       xh, wt_patch, b_patch, nullptr, tmp, nullptr, nullptr,
                       Bc * NPc, Dd, Dd);
    // 3. emb LN + cls concat + pos add -> x
    hipLaunchKernelGGL(k_embed, dim3(Bc * Nn), dim3(256), 0, stream,
                       tmp, cls, pos, emb_g, emb_b, x);

    const int Mrows = Bc * Nn;  // 6304
    for (int l = 0; l < DEPTHc; l++) {
        const float* g  = ln_g + (long)l * Dd;
        const float* bb = ln_b + (long)l * Dd;
        const half_t* Wq = wt_qkv + (long)l * 3 * INNERc * Dd;
        const half_t* Wo = wt_out + (long)l * Dd * Dd;
        const float* bo = b_out + (long)l * Dd;
        hipLaunchKernelGGL((k_ln<half_t>), dim3(Mrows), dim3(256), 0, stream,
                           x, g, bb, xh, (long)Dd, (long)Dd);
        hipLaunchKernelGGL((k_hgemm<0, 0, half_t, 1>), dim3(18 * 50), dim3(256), 0, stream,
                           xh, Wq, nullptr, nullptr, qhb, khb, vhb,
                           Mrows, 3 * INNERc, Dd);
        hipLaunchKernelGGL(k_vtrans, dim3(Bc * NH), dim3(256), 0, stream,
                           vhb, vtb);
        hipLaunchKernelGGL(k_attn, dim3(416), dim3(256), 0, stream,
                           qhb, khb, vtb, xh);
        hipLaunchKernelGGL((k_hgemm<1, 1, float, 0>), dim3(6 * 50), dim3(256), 0, stream,
                           xh, Wo, bo, x, x, nullptr, nullptr,
                           Mrows, Dd, Dd);
    }
    // final LN (cls rows only) -> clsb fp32
    hipLaunchKernelGGL((k_ln<float>), dim3(Bc), dim3(256), 0, stream,
                       x, fin_g, fin_b, clsb, (long)Nn * Dd, (long)Dd);
    // head GEMM (fp32, tiny)
    hipLaunchKernelGGL((k_gemm<1, 0>), dim3(16, 1), dim3(256), 0, stream,
                       clsb, W_head, b_head, nullptr, out, Bc, NCLS, Dd);
}

// Round 7
// 2063.220 us; speedup vs baseline: 4.8974x; 1.2275x over previous
//
#include <hip/hip_runtime.h>
#include <math.h>

// ---------------- problem constants ----------------
constexpr int Bc = 32, Cch = 3, Hh = 224, Ww = 224, Pp = 16;
constexpr int Dd = 768, NH = 12, DHd = 64, INNERc = 768;
constexpr int DEPTHc = 12, NCLS = 1000;
constexpr int NPc = 196, Nn = 197, PD = 768;
constexpr float EPSf = 1e-5f;

typedef _Float16 half_t;
typedef __attribute__((ext_vector_type(8))) _Float16 half8;
typedef __attribute__((ext_vector_type(4))) float f32x4;
typedef __attribute__((ext_vector_type(4))) unsigned int uint32x4;

// ---------------- reduction helpers ----------------
__device__ __forceinline__ float wave_red_sum(float v) {
#pragma unroll
    for (int m = 32; m; m >>= 1) v += __shfl_xor(v, m);
    return v;
}

__device__ __forceinline__ void block_red2(float& s, float& s2, float* red) {
    s = wave_red_sum(s);
    s2 = wave_red_sum(s2);
    int wid = threadIdx.x >> 6, lane = threadIdx.x & 63;
    if (lane == 0) { red[wid] = s; red[4 + wid] = s2; }
    __syncthreads();
    s = red[0] + red[1] + red[2] + red[3];
    s2 = red[4] + red[5] + red[6] + red[7];
}

// ---------------- patchify + patch LN -> f16 ----------------
__global__ __launch_bounds__(256) void k_patch_ln(
        const float* __restrict__ img, const float* __restrict__ g,
        const float* __restrict__ bb, half_t* __restrict__ out) {
    int pid = blockIdx.x;
    int b = pid / NPc, n = pid % NPc;
    int ph = n / 14, pw = n % 14;
    int t = threadIdx.x;
    __shared__ float red[8];
    float v[3];
#pragma unroll
    for (int i = 0; i < 3; i++) {
        int d = t + i * 256;
        int c = d % 3, q = (d / 3) & 15, p = d / 48;
        v[i] = img[((long)(b * Cch + c) * Hh + ph * Pp + p) * Ww + pw * Pp + q];
    }
    float s = v[0] + v[1] + v[2];
    float s2 = v[0] * v[0] + v[1] * v[1] + v[2] * v[2];
    block_red2(s, s2, red);
    float mu = s * (1.f / PD);
    float var = s2 * (1.f / PD) - mu * mu;
    float r = rsqrtf(var + EPSf);
#pragma unroll
    for (int i = 0; i < 3; i++) {
        int d = t + i * 256;
        out[(long)pid * PD + d] = (half_t)((v[i] - mu) * r * g[d] + bb[d]);
    }
}

// ---------------- row LayerNorm (768 wide), templated output ----------------
template <typename T>
__global__ __launch_bounds__(256) void k_ln(
        const float* __restrict__ in, const float* __restrict__ g,
        const float* __restrict__ bb, T* __restrict__ out,
        long in_stride, long out_stride) {
    long row = blockIdx.x;
    const float* ip = in + row * in_stride;
    T* op = out + row * out_stride;
    int t = threadIdx.x;
    __shared__ float red[8];
    float v[3];
#pragma unroll
    for (int i = 0; i < 3; i++) v[i] = ip[t + i * 256];
    float s = v[0] + v[1] + v[2];
    float s2 = v[0] * v[0] + v[1] * v[1] + v[2] * v[2];
    block_red2(s, s2, red);
    float mu = s * (1.f / Dd);
    float var = s2 * (1.f / Dd) - mu * mu;
    float r = rsqrtf(var + EPSf);
#pragma unroll
    for (int i = 0; i < 3; i++) {
        int d = t + i * 256;
        op[d] = (T)((v[i] - mu) * r * g[d] + bb[d]);
    }
}

// ---------------- embed assemble: LN(tmp)+pos, cls+pos ----------------
__global__ __launch_bounds__(256) void k_embed(
        const float* __restrict__ tmp, const float* __restrict__ cls,
        const float* __restrict__ pos, const float* __restrict__ g,
        const float* __restrict__ bb, float* __restrict__ x) {
    int pid = blockIdx.x;
    int b = pid / Nn, n = pid % Nn;
    int t = threadIdx.x;
    float* xp = x + (long)pid * Dd;
    if (n == 0) {
#pragma unroll
        for (int i = 0; i < 3; i++) {
            int d = t + i * 256;
            xp[d] = cls[d] + pos[d];
        }
        return;
    }
    const float* ip = tmp + (long)(b * NPc + n - 1) * Dd;
    __shared__ float red[8];
    float v[3];
#pragma unroll
    for (int i = 0; i < 3; i++) v[i] = ip[t + i * 256];
    float s = v[0] + v[1] + v[2];
    float s2 = v[0] * v[0] + v[1] * v[1] + v[2] * v[2];
    block_red2(s, s2, red);
    float mu = s * (1.f / Dd);
    float var = s2 * (1.f / Dd) - mu * mu;
    float r = rsqrtf(var + EPSf);
#pragma unroll
    for (int i = 0; i < 3; i++) {
        int d = t + i * 256;
        xp[d] = (v[i] - mu) * r * g[d] + bb[d] + pos[(long)n * Dd + d];
    }
}

// ---------------- weight prep: fp32 W[K][N] -> f16 Wt[N][K] ----------------
__global__ __launch_bounds__(256) void k_wprep(
        const float* __restrict__ W, half_t* __restrict__ Wt, int K, int N) {
    W += (long)blockIdx.z * K * N;
    Wt += (long)blockIdx.z * K * N;
    __shared__ float tile[32][33];
    int n = blockIdx.x * 32 + threadIdx.x;
    int k0 = blockIdx.y * 32;
#pragma unroll
    for (int i = 0; i < 4; i++)
        tile[threadIdx.y + i * 8][threadIdx.x] = W[(long)(k0 + threadIdx.y + i * 8) * N + n];
    __syncthreads();
    int kk = k0 + threadIdx.x;
#pragma unroll
    for (int i = 0; i < 4; i++)
        Wt[(long)(blockIdx.x * 32 + threadIdx.y + i * 8) * K + kk] =
            (half_t)tile[threadIdx.x][threadIdx.y + i * 8];
}

// ---------------- f16 MFMA GEMM ----------------
__device__ __forceinline__ half8 lds_frag(const uint32x4 (*L)[8], int row, int slot) {
    union { uint32x4 u; half8 h; } t;
    t.u = L[row][slot];
    return t.h;
}

template <int HASB, int HASR, typename CT, int OMODE>
__global__ __launch_bounds__(256, 2) void k_hgemm(
        const half_t* __restrict__ A, const half_t* __restrict__ Bt,
        const float* __restrict__ bias, const float* __restrict__ res,
        CT* __restrict__ C, CT* __restrict__ C1, CT* __restrict__ C2,
        int M, int N, int K) {
    __shared__ uint32x4 smem[2176];
    uint32x4 (*As)[8] = (uint32x4(*)[8])smem;
    uint32x4 (*Bs)[8] = (uint32x4(*)[8])(smem + 1024);
    const int tid = threadIdx.x;
    const int nwg = gridDim.x;
    const int q8 = nwg >> 3, r8 = nwg & 7;
    const int xc = blockIdx.x & 7, oo = blockIdx.x >> 3;
    const int tile = (xc < r8 ? xc * (q8 + 1) : r8 * (q8 + 1) + (xc - r8) * q8) + oo;
    const int gx = N >> 7;
    const int n0 = (tile % gx) * 128, m0 = (tile / gx) * 128;
    const int lane = tid & 63, w = tid >> 6;
    const int wrr = (w >> 1) * 64, wcc = (w & 1) * 64;
    const int lrow = lane & 15, lgrp = lane >> 4;

    int lm[4], sw[4];
    long gA[4], gB[4];
    const int cb = (tid & 7) * 8;
#pragma unroll
    for (int c = 0; c < 4; ++c) {
        lm[c] = c * 32 + (tid >> 3);
        sw[c] = (tid & 7) ^ (lm[c] & 7);
        int ma = m0 + lm[c];
        if (ma > M - 1) ma = M - 1;
        gA[c] = (long)ma * K + cb;
        gB[c] = (long)(n0 + lm[c]) * K + cb;
    }

    f32x4 acc[4][4] = {};
    uint32x4 ra[4], rb[4];
#pragma unroll
    for (int c = 0; c < 4; ++c) { ra[c] = *(const uint32x4*)(A + gA[c]); rb[c] = *(const uint32x4*)(Bt + gB[c]); }
#pragma unroll
    for (int c = 0; c < 4; ++c) { As[lm[c]][sw[c]] = ra[c]; Bs[lm[c]][sw[c]] = rb[c]; }
    __syncthreads();

    const int nst = K >> 6;
    for (int t = 0; t < nst; ++t) {
        if (t + 1 < nst) {
            const int k0 = (t + 1) << 6;
#pragma unroll
            for (int c = 0; c < 4; ++c) {
                ra[c] = *(const uint32x4*)(A + gA[c] + k0);
                rb[c] = *(const uint32x4*)(Bt + gB[c] + k0);
            }
        }
#pragma unroll
        for (int kh = 0; kh < 2; ++kh) {
            half8 af[4], bf[4];
#pragma unroll
            for (int i2 = 0; i2 < 4; ++i2) {
                int m = wrr + i2 * 16 + lrow;
                af[i2] = lds_frag(As, m, (kh * 4 + lgrp) ^ (m & 7));
                int n = wcc + i2 * 16 + lrow;
                bf[i2] = lds_frag(Bs, n, (kh * 4 + lgrp) ^ (n & 7));
            }
#pragma unroll
            for (int i2 = 0; i2 < 4; ++i2)
#pragma unroll
                for (int j2 = 0; j2 < 4; ++j2)
                    acc[i2][j2] = __builtin_amdgcn_mfma_f32_16x16x32_f16(af[i2], bf[j2], acc[i2][j2], 0, 0, 0);
        }
        if (t + 1 < nst) {
            __syncthreads();
#pragma unroll
            for (int c = 0; c < 4; ++c) { As[lm[c]][sw[c]] = ra[c]; Bs[lm[c]][sw[c]] = rb[c]; }
            __syncthreads();
        }
    }

    if constexpr (sizeof(CT) == 2) {
        __syncthreads();
        half_t* Cs = (half_t*)smem;
#pragma unroll
        for (int i2 = 0; i2 < 4; ++i2)
#pragma unroll
            for (int j2 = 0; j2 < 4; ++j2) {
                int colc = wcc + j2 * 16 + lrow;
                float bv = HASB ? bias[n0 + colc] : 0.f;
#pragma unroll
                for (int q = 0; q < 4; ++q) {
                    int r = wrr + i2 * 16 + lgrp * 4 + q;
                    Cs[r * 136 + colc] = (half_t)(acc[i2][j2][q] + bv);
                }
            }
        __syncthreads();
#pragma unroll
        for (int it = 0; it < 8; ++it) {
            int idx = tid + it * 256;
            int row = idx >> 4, cu = idx & 15;
            int token = m0 + row;
            if (token < M) {
                uint32x4 val = *(const uint32x4*)(Cs + row * 136 + cu * 8);
                if constexpr (OMODE == 1) {
                    int gc = n0 + cu * 8;
                    int which = gc >= 1536 ? 2 : (gc >= 768 ? 1 : 0);
                    int rem = gc - which * 768;
                    int h = rem >> 6, d = rem & 63;
                    int b = token / Nn, nn = token - b * Nn;
                    CT* dst = (which == 0 ? C : which == 1 ? C1 : C2);
                    __builtin_nontemporal_store(val,
                        (uint32x4*)(dst + (((long)(b * NH + h) * Nn + nn) << 6) + d));
                } else {
                    __builtin_nontemporal_store(val,
                        (uint32x4*)(C + (long)token * N + n0 + cu * 8));
                }
            }
        }
    } else {
#pragma unroll
        for (int i2 = 0; i2 < 4; ++i2)
#pragma unroll
            for (int j2 = 0; j2 < 4; ++j2) {
                int colc = n0 + wcc + j2 * 16 + lrow;
                float bv = HASB ? bias[colc] : 0.f;
#pragma unroll
                for (int q = 0; q < 4; ++q) {
                    int r = m0 + wrr + i2 * 16 + lgrp * 4 + q;
                    if (r < M) {
                        float v = acc[i2][j2][q] + bv;
                        if (HASR) v += res[(long)r * N + colc];
                        __builtin_nontemporal_store(v, &C[(long)r * N + colc]);
                    }
                }
            }
    }
}

// ---------------- fp32 tiled GEMM (tiny head GEMM only) ----------------
template <int HASB, int HASR>
__global__ __launch_bounds__(256) void k_gemm(
        const float* __restrict__ A, const float* __restrict__ Wt,
        const float* __restrict__ bias, const float* __restrict__ res,
        float* __restrict__ Co, int M, int Nc, int K) {
    __shared__ float As[16][65];
    __shared__ float Bs[16][68];
    int n0 = blockIdx.x * 64, m0 = blockIdx.y * 64;
    int tid = threadIdx.x;
    int tr = tid / 16, tc = tid % 16;
    int am = tid / 4, ak = (tid % 4) * 4;
    int bk = tid / 16, bn = (tid % 16) * 4;
    float acc[4][4] = {};
    bool nfull = (n0 + 64 <= Nc);
    for (int k0 = 0; k0 < K; k0 += 16) {
        float4 av = {0, 0, 0, 0};
        if (m0 + am < M) av = *(const float4*)&A[(long)(m0 + am) * K + k0 + ak];
        As[ak + 0][am] = av.x; As[ak + 1][am] = av.y;
        As[ak + 2][am] = av.z; As[ak + 3][am] = av.w;
        if (nfull) {
            float4 bv = *(const float4*)&Wt[(long)(k0 + bk) * Nc + n0 + bn];
            Bs[bk][bn + 0] = bv.x; Bs[bk][bn + 1] = bv.y;
            Bs[bk][bn + 2] = bv.z; Bs[bk][bn + 3] = bv.w;
        } else {
#pragma unroll
            for (int u = 0; u < 4; u++)
                Bs[bk][bn + u] = (n0 + bn + u < Nc) ? Wt[(long)(k0 + bk) * Nc + n0 + bn + u] : 0.f;
        }
        __syncthreads();
#pragma unroll
        for (int kk = 0; kk < 16; kk++) {
            float a0 = As[kk][tr * 4 + 0], a1 = As[kk][tr * 4 + 1];
            float a2 = As[kk][tr * 4 + 2], a3 = As[kk][tr * 4 + 3];
            float b0 = Bs[kk][tc], b1 = Bs[kk][tc + 16];
            float b2 = Bs[kk][tc + 32], b3 = Bs[kk][tc + 48];
            acc[0][0] += a0 * b0; acc[0][1] += a0 * b1; acc[0][2] += a0 * b2; acc[0][3] += a0 * b3;
            acc[1][0] += a1 * b0; acc[1][1] += a1 * b1; acc[1][2] += a1 * b2; acc[1][3] += a1 * b3;
            acc[2][0] += a2 * b0; acc[2][1] += a2 * b1; acc[2][2] += a2 * b2; acc[2][3] += a2 * b3;
            acc[3][0] += a3 * b0; acc[3][1] += a3 * b1; acc[3][2] += a3 * b2; acc[3][3] += a3 * b3;
        }
        __syncthreads();
    }
#pragma unroll
    for (int i = 0; i < 4; i++) {
        int r = m0 + tr * 4 + i;
        if (r >= M) continue;
#pragma unroll
        for (int j = 0; j < 4; j++) {
            int c0 = n0 + tc + j * 16;
            if (c0 >= Nc) continue;
            float v = acc[i][j];
            if (HASB) v += bias[c0];
            if (HASR) v += res[(long)r * Nc + c0];
            Co[(long)r * Nc + c0] = v;
        }
    }
}

// ---------------- V transpose: [b,h,n,64] -> [b,h,64,224] (n zero-padded) ----------------
__global__ __launch_bounds__(256) void k_vtrans(
        const half_t* __restrict__ vh, half_t* __restrict__ vt) {
    const int bh = blockIdx.x;
    __shared__ half_t vsT[Nn][68];
    const int tid = threadIdx.x;
    const half_t* Vp = vh + (long)bh * Nn * 64;
    for (int idx = tid; idx < Nn * 8; idx += 256) {
        int r = idx >> 3, c8 = (idx & 7) * 8;
        *(half8*)&vsT[r][c8] = *(const half8*)&Vp[(long)r * 64 + c8];
    }
    __syncthreads();
    half_t* Tp = vt + (long)bh * 64 * 224;
    for (int idx = tid; idx < 64 * 112; idx += 256) {
        int d = idx / 112, p = idx % 112;
        int n0 = p * 2;
        union { unsigned int u; half_t h[2]; } t;
        t.h[0] = (n0 < Nn) ? vsT[n0][d] : (half_t)0.f;
        t.h[1] = (n0 + 1 < Nn) ? vsT[n0 + 1][d] : (half_t)0.f;
        *(unsigned int*)&Tp[(long)d * 224 + n0] = t.u;
    }
}

// ---------------- attention stats: per-(b,i,j) cross-head mu & rsqrt(var) ----------------
// Grid 1664 (XCD-chunked), 4 waves; wave = one (b, i-tile, j-tile), 12 heads x 2 MFMA.
// All stats in registers; S sequence identical to k_attn2's recompute -> exact.
__global__ __launch_bounds__(256) void k_stats(
        const half_t* __restrict__ qh, const half_t* __restrict__ kh,
        float* __restrict__ muG, float* __restrict__ rsG) {
    const int tile = (blockIdx.x & 7) * 208 + (blockIdx.x >> 3);  // 1664 = 8*208
    const int b = tile / 52, rem = tile % 52;                     // 52 tiles per b
    const int it = rem >> 2, jtg = rem & 3;
    const int w = threadIdx.x >> 6, lane = threadIdx.x & 63;
    const int jt = jtg * 4 + w;
    if (jt > 12) return;
    const int lrow = lane & 15, lg = lane >> 4;
    const int i0 = it * 16, j0 = jt * 16;
    const int arow = min(i0 + lrow, Nn - 1);
    const int jr = min(j0 + lrow, Nn - 1);
    const int hbase = b * NH;

    float sv[4] = {}, sq[4] = {};
#pragma unroll
    for (int h = 0; h < NH; h++) {
        const half_t* Qp = qh + ((long)(hbase + h) * Nn) * 64;
        const half_t* Kp = kh + ((long)(hbase + h) * Nn) * 64;
        half8 af0 = *(const half8*)&Qp[(long)arow * 64 + lg * 8];
        half8 af1 = *(const half8*)&Qp[(long)arow * 64 + 32 + lg * 8];
        half8 bf0 = *(const half8*)&Kp[(long)jr * 64 + lg * 8];
        half8 bf1 = *(const half8*)&Kp[(long)jr * 64 + 32 + lg * 8];
        f32x4 acc = {};
        acc = __builtin_amdgcn_mfma_f32_16x16x32_f16(af0, bf0, acc, 0, 0, 0);
        acc = __builtin_amdgcn_mfma_f32_16x16x32_f16(af1, bf1, acc, 0, 0, 0);
#pragma unroll
        for (int q = 0; q < 4; q++) { sv[q] += acc[q]; sq[q] += acc[q] * acc[q]; }
    }
#pragma unroll
    for (int q = 0; q < 4; q++) {
        int i = i0 + lg * 4 + q, j = j0 + lrow;
        if (i < Nn && j < Nn) {
            float mu = sv[q] * (1.f / NH);
            float var = (sq[q] - sv[q] * mu) * (1.f / (NH - 1));
            long idx = (long)b * (Nn * Nn) + (long)i * Nn + j;
            muG[idx] = mu;
            rsG[idx] = rsqrtf(var);
        }
    }
}

// ---------------- attention per head: S recompute + z-score + softmax + PV ----------------
// Grid 4992 (XCD-chunked), 1 wave per (b,h,i-tile). LDS = one P tile (7.4 KB).
__global__ __launch_bounds__(64) void k_attn2(
        const half_t* __restrict__ qh, const half_t* __restrict__ kh,
        const half_t* __restrict__ vt, const float* __restrict__ muG,
        const float* __restrict__ rsG, half_t* __restrict__ o) {
    __shared__ half_t PB[16][232];
    const int tile = (blockIdx.x & 7) * 624 + (blockIdx.x >> 3);  // 4992 = 8*624
    const int bh = tile / 13, it = tile % 13;
    const int b = bh / NH, h = bh % NH;
    const int i0 = it * 16;
    const int lane = threadIdx.x;
    const int lrow = lane & 15, lg = lane >> 4;
    const int arow = min(i0 + lrow, Nn - 1);

    // zero PB pad cols 208..223 (read by PV, never written by P store)
    for (int idx = lane; idx < 16 * 12; idx += 64) {
        int rr = idx / 12, u = idx % 12;
        *(unsigned int*)&PB[rr][208 + u * 2] = 0u;
    }

    const half_t* Qp = qh + ((long)bh * Nn) * 64;
    const half_t* Kp = kh + ((long)bh * Nn) * 64;
    half8 af0 = *(const half8*)&Qp[(long)arow * 64 + lg * 8];
    half8 af1 = *(const half8*)&Qp[(long)arow * 64 + 32 + lg * 8];
    const float* muB = muG + (long)b * (Nn * Nn);
    const float* rsB = rsG + (long)b * (Nn * Nn);

    float ez[13][4];
    float mx[4] = {-1e30f, -1e30f, -1e30f, -1e30f};
#pragma unroll
    for (int jt = 0; jt < 13; jt++) {
        int jr = min(jt * 16 + lrow, Nn - 1);
        half8 bf0 = *(const half8*)&Kp[(long)jr * 64 + lg * 8];
        half8 bf1 = *(const half8*)&Kp[(long)jr * 64 + 32 + lg * 8];
        f32x4 acc = {};
        acc = __builtin_amdgcn_mfma_f32_16x16x32_f16(af0, bf0, acc, 0, 0, 0);
        acc = __builtin_amdgcn_mfma_f32_16x16x32_f16(af1, bf1, acc, 0, 0, 0);
        int j = jt * 16 + lrow;
        int jc = min(j, Nn - 1);
#pragma unroll
        for (int q = 0; q < 4; q++) {
            int ic = min(i0 + lg * 4 + q, Nn - 1);
            long sidx = (long)ic * Nn + jc;
            float z = (acc[q] - muB[sidx]) * rsB[sidx];
            if (j > Nn - 1) z = -1e30f;
            ez[jt][q] = z;
            mx[q] = fmaxf(mx[q], z);
        }
    }
#pragma unroll
    for (int st = 1; st <= 8; st <<= 1)
#pragma unroll
        for (int q = 0; q < 4; q++) mx[q] = fmaxf(mx[q], __shfl_xor(mx[q], st));
    float sm[4] = {0.f, 0.f, 0.f, 0.f};
#pragma unroll
    for (int jt = 0; jt < 13; jt++)
#pragma unroll
        for (int q = 0; q < 4; q++) {
            float e = __expf(ez[jt][q] - mx[q]);
            ez[jt][q] = e;
            sm[q] += e;
        }
#pragma unroll
    for (int st = 1; st <= 8; st <<= 1)
#pragma unroll
        for (int q = 0; q < 4; q++) sm[q] += __shfl_xor(sm[q], st);
    float inv[4];
#pragma unroll
    for (int q = 0; q < 4; q++) inv[q] = 1.f / sm[q];
#pragma unroll
    for (int jt = 0; jt < 13; jt++)
#pragma unroll
        for (int q = 0; q < 4; q++)
            PB[lg * 4 + q][jt * 16 + lrow] = (half_t)(ez[jt][q] * inv[q]);
    __syncthreads();

    const half_t* Vtp = vt + ((long)bh * 64) * 224;
#pragma unroll
    for (int dt = 0; dt < 4; dt++) {
        f32x4 oacc = {};
#pragma unroll
        for (int kt = 0; kt < 7; kt++) {
            half8 pa = *(const half8*)&PB[lrow][kt * 32 + lg * 8];
            half8 vb = *(const half8*)&Vtp[(long)(dt * 16 + lrow) * 224 + kt * 32 + lg * 8];
            oacc = __builtin_amdgcn_mfma_f32_16x16x32_f16(pa, vb, oacc, 0, 0, 0);
        }
#pragma unroll
        for (int q = 0; q < 4; q++) {
            int i = i0 + lg * 4 + q;
            if (i < Nn)
                o[((long)(b * Nn) + i) * INNERc + h * 64 + dt * 16 + lrow] = (half_t)oacc[q];
        }
    }
}

// ---------------- host launcher ----------------
extern "C" void kernel_launch(void* const* d_in, const int* in_sizes, int n_in,
                              void* d_out, int out_size, void* d_ws, size_t ws_size,
                              hipStream_t stream) {
    const float* img     = (const float*)d_in[0];
    const float* patch_g = (const float*)d_in[2];
    const float* patch_b = (const float*)d_in[3];
    const float* W_patch = (const float*)d_in[4];
    const float* b_patch = (const float*)d_in[5];
    const float* emb_g   = (const float*)d_in[6];
    const float* emb_b   = (const float*)d_in[7];
    const float* pos     = (const float*)d_in[8];
    const float* cls     = (const float*)d_in[9];
    const float* ln_g    = (const float*)d_in[10];
    const float* ln_b    = (const float*)d_in[11];
    const float* W_qkv   = (const float*)d_in[12];
    const float* W_out   = (const float*)d_in[13];
    const float* b_out   = (const float*)d_in[14];
    const float* fin_g   = (const float*)d_in[15];
    const float* fin_b   = (const float*)d_in[16];
    const float* W_head  = (const float*)d_in[17];
    const float* b_head  = (const float*)d_in[18];
    float* out = (float*)d_out;

    const long SZ_XD  = (long)Bc * Nn * Dd;          // 4,841,472
    const long SZ_HD  = (long)Bc * NH * Nn * DHd;    // 4,841,472
    const long SZ_VT  = (long)Bc * NH * 64 * 224;    // 5,505,024
    const long SZ_TMP = (long)Bc * NPc * Dd;
    const long SZ_MU  = (long)Bc * Nn * Nn + 4096;   // + pad

    float* x    = (float*)d_ws;
    float* tmp  = x + SZ_XD;
    float* clsb = tmp + SZ_TMP;
    float* muG  = clsb + 32 * 768;
    float* rsG  = muG + SZ_MU;
    half_t* xh       = (half_t*)(rsG + SZ_MU);
    half_t* qhb      = xh + SZ_XD;
    half_t* khb      = qhb + SZ_HD;
    half_t* vhb      = khb + SZ_HD;
    half_t* vtb      = vhb + SZ_HD;
    half_t* wt_patch = vtb + SZ_VT;
    half_t* wt_qkv   = wt_patch + (long)Dd * Dd;
    half_t* wt_out   = wt_qkv + (long)DEPTHc * 3 * INNERc * Dd;

    // ---- weight prep: fp32 [K][N] -> f16 [N][K] ----
    hipLaunchKernelGGL(k_wprep, dim3(Dd / 32, Dd / 32, 1), dim3(32, 8), 0, stream,
                       W_patch, wt_patch, Dd, Dd);
    hipLaunchKernelGGL(k_wprep, dim3(3 * INNERc / 32, Dd / 32, DEPTHc), dim3(32, 8), 0, stream,
                       W_qkv, wt_qkv, Dd, 3 * INNERc);
    hipLaunchKernelGGL(k_wprep, dim3(Dd / 32, Dd / 32, DEPTHc), dim3(32, 8), 0, stream,
                       W_out, wt_out, Dd, Dd);

    // 1. patchify + patch LN -> xh (f16)
    hipLaunchKernelGGL(k_patch_ln, dim3(Bc * NPc), dim3(256), 0, stream,
                       img, patch_g, patch_b, xh);
    // 2. patch GEMM (+b_patch) -> tmp fp32
    hipLaunchKernelGGL((k_hgemm<1, 0, float, 0>), dim3(6 * 49), dim3(256), 0, stream,
                       xh, wt_patch, b_patch, nullptr, tmp, nullptr, nullptr,
                       Bc * NPc, Dd, Dd);
    // 3. emb LN + cls concat + pos add -> x
    hipLaunchKernelGGL(k_embed, dim3(Bc * Nn), dim3(256), 0, stream,
                       tmp, cls, pos, emb_g, emb_b, x);

    const int Mrows = Bc * Nn;  // 6304
    for (int l = 0; l < DEPTHc; l++) {
        const float* g  = ln_g + (long)l * Dd;
        const float* bb = ln_b + (long)l * Dd;
        const half_t* Wq = wt_qkv + (long)l * 3 * INNERc * Dd;
        const half_t* Wo = wt_out + (long)l * Dd * Dd;
        const float* bo = b_out + (long)l * Dd;
        hipLaunchKernelGGL((k_ln<half_t>), dim3(Mrows), dim3(256), 0, stream,
                           x, g, bb, xh, (long)Dd, (long)Dd);
        hipLaunchKernelGGL((k_hgemm<0, 0, half_t, 1>), dim3(18 * 50), dim3(256), 0, stream,
                           xh, Wq, nullptr, nullptr, qhb, khb, vhb,
                           Mrows, 3 * INNERc, Dd);
        hipLaunchKernelGGL(k_vtrans, dim3(Bc * NH), dim3(256), 0, stream,
                           vhb, vtb);
        hipLaunchKernelGGL(k_stats, dim3(1664), dim3(256), 0, stream,
                           qhb, khb, muG, rsG);
        hipLaunchKernelGGL(k_attn2, dim3(4992), dim3(64), 0, stream,
                           qhb, khb, vtb, muG, rsG, xh);
        hipLaunchKernelGGL((k_hgemm<1, 1, float, 0>), dim3(6 * 50), dim3(256), 0, stream,
                           xh, Wo, bo, x, x, nullptr, nullptr,
                           Mrows, Dd, Dd);
    }
    // final LN (cls rows only) -> clsb fp32
    hipLaunchKernelGGL((k_ln<float>), dim3(Bc), dim3(256), 0, stream,
                       x, fin_g, fin_b, clsb, (long)Nn * Dd, (long)Dd);
    // head GEMM (fp32, tiny)
    hipLaunchKernelGGL((k_gemm<1, 0>), dim3(16, 1), dim3(256), 0, stream,
                       clsb, W_head, b_head, nullptr, out, Bc, NCLS, Dd);
}

// Round 8
// 1880.868 us; speedup vs baseline: 5.3722x; 1.0970x over previous
//
#include <hip/hip_runtime.h>
#include <math.h>

// ---------------- problem constants ----------------
constexpr int Bc = 32, Cch = 3, Hh = 224, Ww = 224, Pp = 16;
constexpr int Dd = 768, NH = 12, DHd = 64, INNERc = 768;
constexpr int DEPTHc = 12, NCLS = 1000;
constexpr int NPc = 196, Nn = 197, PD = 768;
constexpr float EPSf = 1e-5f;

typedef _Float16 half_t;
typedef __attribute__((ext_vector_type(8))) _Float16 half8;
typedef __attribute__((ext_vector_type(4))) float f32x4;
typedef __attribute__((ext_vector_type(4))) unsigned int uint32x4;

// ---------------- reduction helpers ----------------
__device__ __forceinline__ float wave_red_sum(float v) {
#pragma unroll
    for (int m = 32; m; m >>= 1) v += __shfl_xor(v, m);
    return v;
}

__device__ __forceinline__ void block_red2(float& s, float& s2, float* red) {
    s = wave_red_sum(s);
    s2 = wave_red_sum(s2);
    int wid = threadIdx.x >> 6, lane = threadIdx.x & 63;
    if (lane == 0) { red[wid] = s; red[4 + wid] = s2; }
    __syncthreads();
    s = red[0] + red[1] + red[2] + red[3];
    s2 = red[4] + red[5] + red[6] + red[7];
}

// ---------------- patchify + patch LN -> f16 ----------------
__global__ __launch_bounds__(256) void k_patch_ln(
        const float* __restrict__ img, const float* __restrict__ g,
        const float* __restrict__ bb, half_t* __restrict__ out) {
    int pid = blockIdx.x;
    int b = pid / NPc, n = pid % NPc;
    int ph = n / 14, pw = n % 14;
    int t = threadIdx.x;
    __shared__ float red[8];
    float v[3];
#pragma unroll
    for (int i = 0; i < 3; i++) {
        int d = t + i * 256;
        int c = d % 3, q = (d / 3) & 15, p = d / 48;
        v[i] = img[((long)(b * Cch + c) * Hh + ph * Pp + p) * Ww + pw * Pp + q];
    }
    float s = v[0] + v[1] + v[2];
    float s2 = v[0] * v[0] + v[1] * v[1] + v[2] * v[2];
    block_red2(s, s2, red);
    float mu = s * (1.f / PD);
    float var = s2 * (1.f / PD) - mu * mu;
    float r = rsqrtf(var + EPSf);
#pragma unroll
    for (int i = 0; i < 3; i++) {
        int d = t + i * 256;
        out[(long)pid * PD + d] = (half_t)((v[i] - mu) * r * g[d] + bb[d]);
    }
}

// ---------------- row LayerNorm (768 wide), templated output ----------------
template <typename T>
__global__ __launch_bounds__(256) void k_ln(
        const float* __restrict__ in, const float* __restrict__ g,
        const float* __restrict__ bb, T* __restrict__ out,
        long in_stride, long out_stride) {
    long row = blockIdx.x;
    const float* ip = in + row * in_stride;
    T* op = out + row * out_stride;
    int t = threadIdx.x;
    __shared__ float red[8];
    float v[3];
#pragma unroll
    for (int i = 0; i < 3; i++) v[i] = ip[t + i * 256];
    float s = v[0] + v[1] + v[2];
    float s2 = v[0] * v[0] + v[1] * v[1] + v[2] * v[2];
    block_red2(s, s2, red);
    float mu = s * (1.f / Dd);
    float var = s2 * (1.f / Dd) - mu * mu;
    float r = rsqrtf(var + EPSf);
#pragma unroll
    for (int i = 0; i < 3; i++) {
        int d = t + i * 256;
        op[d] = (T)((v[i] - mu) * r * g[d] + bb[d]);
    }
}

// ---------------- embed assemble: LN(tmp)+pos, cls+pos ----------------
__global__ __launch_bounds__(256) void k_embed(
        const float* __restrict__ tmp, const float* __restrict__ cls,
        const float* __restrict__ pos, const float* __restrict__ g,
        const float* __restrict__ bb, float* __restrict__ x) {
    int pid = blockIdx.x;
    int b = pid / Nn, n = pid % Nn;
    int t = threadIdx.x;
    float* xp = x + (long)pid * Dd;
    if (n == 0) {
#pragma unroll
        for (int i = 0; i < 3; i++) {
            int d = t + i * 256;
            xp[d] = cls[d] + pos[d];
        }
        return;
    }
    const float* ip = tmp + (long)(b * NPc + n - 1) * Dd;
    __shared__ float red[8];
    float v[3];
#pragma unroll
    for (int i = 0; i < 3; i++) v[i] = ip[t + i * 256];
    float s = v[0] + v[1] + v[2];
    float s2 = v[0] * v[0] + v[1] * v[1] + v[2] * v[2];
    block_red2(s, s2, red);
    float mu = s * (1.f / Dd);
    float var = s2 * (1.f / Dd) - mu * mu;
    float r = rsqrtf(var + EPSf);
#pragma unroll
    for (int i = 0; i < 3; i++) {
        int d = t + i * 256;
        xp[d] = (v[i] - mu) * r * g[d] + bb[d] + pos[(long)n * Dd + d];
    }
}

// ---------------- weight prep: fp32 W[K][N] -> f16 Wt[N][K] ----------------
__global__ __launch_bounds__(256) void k_wprep(
        const float* __restrict__ W, half_t* __restrict__ Wt, int K, int N) {
    W += (long)blockIdx.z * K * N;
    Wt += (long)blockIdx.z * K * N;
    __shared__ float tile[32][33];
    int n = blockIdx.x * 32 + threadIdx.x;
    int k0 = blockIdx.y * 32;
#pragma unroll
    for (int i = 0; i < 4; i++)
        tile[threadIdx.y + i * 8][threadIdx.x] = W[(long)(k0 + threadIdx.y + i * 8) * N + n];
    __syncthreads();
    int kk = k0 + threadIdx.x;
#pragma unroll
    for (int i = 0; i < 4; i++)
        Wt[(long)(blockIdx.x * 32 + threadIdx.y + i * 8) * K + kk] =
            (half_t)tile[threadIdx.x][threadIdx.y + i * 8];
}

// ---------------- head weight prep: fp32 [768][1000] -> f16 [1024][768] (pad 0) --------
__global__ __launch_bounds__(256) void k_wprep_head(
        const float* __restrict__ W, half_t* __restrict__ Wt) {
    __shared__ float tile[32][33];
    int n = blockIdx.x * 32 + threadIdx.x;
    int k0 = blockIdx.y * 32;
#pragma unroll
    for (int i = 0; i < 4; i++)
        tile[threadIdx.y + i * 8][threadIdx.x] =
            (n < NCLS) ? W[(long)(k0 + threadIdx.y + i * 8) * NCLS + n] : 0.f;
    __syncthreads();
    int kk = k0 + threadIdx.x;
#pragma unroll
    for (int i = 0; i < 4; i++)
        Wt[(long)(blockIdx.x * 32 + threadIdx.y + i * 8) * Dd + kk] =
            (half_t)tile[threadIdx.x][threadIdx.y + i * 8];
}

// ---------------- head GEMM: one thread per (row,col), f16 dot ----------------
__global__ __launch_bounds__(256) void k_head(
        const half_t* __restrict__ Ah, const half_t* __restrict__ Wh,
        const float* __restrict__ bias, float* __restrict__ out) {
    int idx = blockIdx.x * 256 + threadIdx.x;
    int row = idx >> 10, col = idx & 1023;
    if (col >= NCLS) return;
    const half_t* ap = Ah + (long)row * Dd;
    const half_t* wp = Wh + (long)col * Dd;
    float acc = 0.f;
#pragma unroll
    for (int k = 0; k < 96; k++) {
        half8 a = *(const half8*)&ap[k * 8];
        half8 w = *(const half8*)&wp[k * 8];
#pragma unroll
        for (int u = 0; u < 8; u++) acc += (float)a[u] * (float)w[u];
    }
    out[(long)row * NCLS + col] = acc + bias[col];
}

// ---------------- f16 MFMA GEMM ----------------
__device__ __forceinline__ half8 lds_frag(const uint32x4 (*L)[8], int row, int slot) {
    union { uint32x4 u; half8 h; } t;
    t.u = L[row][slot];
    return t.h;
}

template <int HASB, int HASR, typename CT, int OMODE>
__global__ __launch_bounds__(256, 2) void k_hgemm(
        const half_t* __restrict__ A, const half_t* __restrict__ Bt,
        const float* __restrict__ bias, const float* __restrict__ res,
        CT* __restrict__ C, CT* __restrict__ C1, CT* __restrict__ C2,
        int M, int N, int K) {
    __shared__ uint32x4 smem[2176];
    uint32x4 (*As)[8] = (uint32x4(*)[8])smem;
    uint32x4 (*Bs)[8] = (uint32x4(*)[8])(smem + 1024);
    const int tid = threadIdx.x;
    const int nwg = gridDim.x;
    const int q8 = nwg >> 3, r8 = nwg & 7;
    const int xc = blockIdx.x & 7, oo = blockIdx.x >> 3;
    const int tile = (xc < r8 ? xc * (q8 + 1) : r8 * (q8 + 1) + (xc - r8) * q8) + oo;
    const int gx = N >> 7;
    const int n0 = (tile % gx) * 128, m0 = (tile / gx) * 128;
    const int lane = tid & 63, w = tid >> 6;
    const int wrr = (w >> 1) * 64, wcc = (w & 1) * 64;
    const int lrow = lane & 15, lgrp = lane >> 4;

    int lm[4], sw[4];
    long gA[4], gB[4];
    const int cb = (tid & 7) * 8;
#pragma unroll
    for (int c = 0; c < 4; ++c) {
        lm[c] = c * 32 + (tid >> 3);
        sw[c] = (tid & 7) ^ (lm[c] & 7);
        int ma = m0 + lm[c];
        if (ma > M - 1) ma = M - 1;
        gA[c] = (long)ma * K + cb;
        gB[c] = (long)(n0 + lm[c]) * K + cb;
    }

    f32x4 acc[4][4] = {};
    uint32x4 ra[4], rb[4];
#pragma unroll
    for (int c = 0; c < 4; ++c) { ra[c] = *(const uint32x4*)(A + gA[c]); rb[c] = *(const uint32x4*)(Bt + gB[c]); }
#pragma unroll
    for (int c = 0; c < 4; ++c) { As[lm[c]][sw[c]] = ra[c]; Bs[lm[c]][sw[c]] = rb[c]; }
    __syncthreads();

    const int nst = K >> 6;
    for (int t = 0; t < nst; ++t) {
        if (t + 1 < nst) {
            const int k0 = (t + 1) << 6;
#pragma unroll
            for (int c = 0; c < 4; ++c) {
                ra[c] = *(const uint32x4*)(A + gA[c] + k0);
                rb[c] = *(const uint32x4*)(Bt + gB[c] + k0);
            }
        }
#pragma unroll
        for (int kh = 0; kh < 2; ++kh) {
            half8 af[4], bf[4];
#pragma unroll
            for (int i2 = 0; i2 < 4; ++i2) {
                int m = wrr + i2 * 16 + lrow;
                af[i2] = lds_frag(As, m, (kh * 4 + lgrp) ^ (m & 7));
                int n = wcc + i2 * 16 + lrow;
                bf[i2] = lds_frag(Bs, n, (kh * 4 + lgrp) ^ (n & 7));
            }
#pragma unroll
            for (int i2 = 0; i2 < 4; ++i2)
#pragma unroll
                for (int j2 = 0; j2 < 4; ++j2)
                    acc[i2][j2] = __builtin_amdgcn_mfma_f32_16x16x32_f16(af[i2], bf[j2], acc[i2][j2], 0, 0, 0);
        }
        if (t + 1 < nst) {
            __syncthreads();
#pragma unroll
            for (int c = 0; c < 4; ++c) { As[lm[c]][sw[c]] = ra[c]; Bs[lm[c]][sw[c]] = rb[c]; }
            __syncthreads();
        }
    }

    if constexpr (sizeof(CT) == 2) {
        __syncthreads();
        half_t* Cs = (half_t*)smem;
#pragma unroll
        for (int i2 = 0; i2 < 4; ++i2)
#pragma unroll
            for (int j2 = 0; j2 < 4; ++j2) {
                int colc = wcc + j2 * 16 + lrow;
                float bv = HASB ? bias[n0 + colc] : 0.f;
#pragma unroll
                for (int q = 0; q < 4; ++q) {
                    int r = wrr + i2 * 16 + lgrp * 4 + q;
                    Cs[r * 136 + colc] = (half_t)(acc[i2][j2][q] + bv);
                }
            }
        __syncthreads();
#pragma unroll
        for (int it = 0; it < 8; ++it) {
            int idx = tid + it * 256;
            int row = idx >> 4, cu = idx & 15;
            int token = m0 + row;
            if (token < M) {
                uint32x4 val = *(const uint32x4*)(Cs + row * 136 + cu * 8);
                if constexpr (OMODE == 1) {
                    int gc = n0 + cu * 8;
                    int which = gc >= 1536 ? 2 : (gc >= 768 ? 1 : 0);
                    int rem = gc - which * 768;
                    int h = rem >> 6, d = rem & 63;
                    int b = token / Nn, nn = token - b * Nn;
                    CT* dst = (which == 0 ? C : which == 1 ? C1 : C2);
                    __builtin_nontemporal_store(val,
                        (uint32x4*)(dst + (((long)(b * NH + h) * Nn + nn) << 6) + d));
                } else {
                    __builtin_nontemporal_store(val,
                        (uint32x4*)(C + (long)token * N + n0 + cu * 8));
                }
            }
        }
    } else {
#pragma unroll
        for (int i2 = 0; i2 < 4; ++i2)
#pragma unroll
            for (int j2 = 0; j2 < 4; ++j2) {
                int colc = n0 + wcc + j2 * 16 + lrow;
                float bv = HASB ? bias[colc] : 0.f;
#pragma unroll
                for (int q = 0; q < 4; ++q) {
                    int r = m0 + wrr + i2 * 16 + lgrp * 4 + q;
                    if (r < M) {
                        float v = acc[i2][j2][q] + bv;
                        if (HASR) v += res[(long)r * N + colc];
                        __builtin_nontemporal_store(v, &C[(long)r * N + colc]);
                    }
                }
            }
    }
}

// ---------------- V transpose: [b,h,n,64] -> [b,h,64,224] (n zero-padded) ----------------
__global__ __launch_bounds__(256) void k_vtrans(
        const half_t* __restrict__ vh, half_t* __restrict__ vt) {
    const int bh = blockIdx.x;
    __shared__ half_t vsT[Nn][68];
    const int tid = threadIdx.x;
    const half_t* Vp = vh + (long)bh * Nn * 64;
    for (int idx = tid; idx < Nn * 8; idx += 256) {
        int r = idx >> 3, c8 = (idx & 7) * 8;
        *(half8*)&vsT[r][c8] = *(const half8*)&Vp[(long)r * 64 + c8];
    }
    __syncthreads();
    half_t* Tp = vt + (long)bh * 64 * 224;
    for (int idx = tid; idx < 64 * 112; idx += 256) {
        int d = idx / 112, p = idx % 112;
        int n0 = p * 2;
        union { unsigned int u; half_t h[2]; } t;
        t.h[0] = (n0 < Nn) ? vsT[n0][d] : (half_t)0.f;
        t.h[1] = (n0 + 1 < Nn) ? vsT[n0 + 1][d] : (half_t)0.f;
        *(unsigned int*)&Tp[(long)d * 224 + n0] = t.u;
    }
}

// ---------------- attention stats: cross-head mu & rsqrt(var), fragment layout --------
// Grid 1352 (= 8*169, bijective XCD chunks), 4 waves; wave = one (b,it,jt) task.
// Output layout matches the MFMA C-fragment: [b][it][jt][lane] f32x4 (q=0..3).
__global__ __launch_bounds__(256) void k_stats(
        const half_t* __restrict__ qh, const half_t* __restrict__ kh,
        f32x4* __restrict__ muT, f32x4* __restrict__ rsT) {
    const int blk = (blockIdx.x & 7) * 169 + (blockIdx.x >> 3);   // 1352 = 8*169
    const int w = threadIdx.x >> 6, lane = threadIdx.x & 63;
    const int task = blk * 4 + w;                                  // 5408 = 32*169
    const int b = task / 169, r = task % 169;
    const int it = r / 13, jt = r % 13;
    const int lrow = lane & 15, lg = lane >> 4;
    const int i0 = it * 16, j0 = jt * 16;
    const int arow = min(i0 + lrow, Nn - 1);
    const int jr = min(j0 + lrow, Nn - 1);
    const int hbase = b * NH;

    float sv[4] = {}, sq[4] = {};
#pragma unroll
    for (int h = 0; h < NH; h++) {
        const half_t* Qp = qh + ((long)(hbase + h) * Nn) * 64;
        const half_t* Kp = kh + ((long)(hbase + h) * Nn) * 64;
        half8 af0 = *(const half8*)&Qp[(long)arow * 64 + lg * 8];
        half8 af1 = *(const half8*)&Qp[(long)arow * 64 + 32 + lg * 8];
        half8 bf0 = *(const half8*)&Kp[(long)jr * 64 + lg * 8];
        half8 bf1 = *(const half8*)&Kp[(long)jr * 64 + 32 + lg * 8];
        f32x4 acc = {};
        acc = __builtin_amdgcn_mfma_f32_16x16x32_f16(af0, bf0, acc, 0, 0, 0);
        acc = __builtin_amdgcn_mfma_f32_16x16x32_f16(af1, bf1, acc, 0, 0, 0);
#pragma unroll
        for (int q = 0; q < 4; q++) { sv[q] += acc[q]; sq[q] += acc[q] * acc[q]; }
    }
    f32x4 muv, rsv;
#pragma unroll
    for (int q = 0; q < 4; q++) {
        float mu = sv[q] * (1.f / NH);
        float var = (sq[q] - sv[q] * mu) * (1.f / (NH - 1));
        muv[q] = mu;
        rsv[q] = rsqrtf(var);
    }
    long idx = ((long)(b * 13 + it) * 13 + jt) * 64 + lane;
    muT[idx] = muv;
    rsT[idx] = rsv;
}

// ---------------- attention per head: S recompute + z-score + softmax + PV ----------------
// Grid 4992 (XCD-chunked), 1 wave per (b,h,i-tile). mu/rs read as coalesced f32x4.
__global__ __launch_bounds__(64) void k_attn2(
        const half_t* __restrict__ qh, const half_t* __restrict__ kh,
        const half_t* __restrict__ vt, const f32x4* __restrict__ muT,
        const f32x4* __restrict__ rsT, half_t* __restrict__ o) {
    __shared__ half_t PB[16][232];
    const int tile = (blockIdx.x & 7) * 624 + (blockIdx.x >> 3);  // 4992 = 8*624
    const int bh = tile / 13, it = tile % 13;
    const int b = bh / NH, h = bh % NH;
    const int i0 = it * 16;
    const int lane = threadIdx.x;
    const int lrow = lane & 15, lg = lane >> 4;
    const int arow = min(i0 + lrow, Nn - 1);

    // zero PB pad cols 208..223 (read by PV, never written by P store)
    for (int idx = lane; idx < 16 * 12; idx += 64) {
        int rr = idx / 12, u = idx % 12;
        *(unsigned int*)&PB[rr][208 + u * 2] = 0u;
    }

    const half_t* Qp = qh + ((long)bh * Nn) * 64;
    const half_t* Kp = kh + ((long)bh * Nn) * 64;
    half8 af0 = *(const half8*)&Qp[(long)arow * 64 + lg * 8];
    half8 af1 = *(const half8*)&Qp[(long)arow * 64 + 32 + lg * 8];
    const f32x4* muB = muT + ((long)(b * 13 + it) * 13) * 64 + lane;
    const f32x4* rsB = rsT + ((long)(b * 13 + it) * 13) * 64 + lane;

    float ez[13][4];
    float mx[4] = {-1e30f, -1e30f, -1e30f, -1e30f};
#pragma unroll
    for (int jt = 0; jt < 13; jt++) {
        int jr = min(jt * 16 + lrow, Nn - 1);
        half8 bf0 = *(const half8*)&Kp[(long)jr * 64 + lg * 8];
        half8 bf1 = *(const half8*)&Kp[(long)jr * 64 + 32 + lg * 8];
        f32x4 acc = {};
        acc = __builtin_amdgcn_mfma_f32_16x16x32_f16(af0, bf0, acc, 0, 0, 0);
        acc = __builtin_amdgcn_mfma_f32_16x16x32_f16(af1, bf1, acc, 0, 0, 0);
        f32x4 mu4 = muB[jt * 64];
        f32x4 rs4 = rsB[jt * 64];
        bool joob = (jt * 16 + lrow) > Nn - 1;
#pragma unroll
        for (int q = 0; q < 4; q++) {
            float z = (acc[q] - mu4[q]) * rs4[q];
            if (joob) z = -1e30f;
            ez[jt][q] = z;
            mx[q] = fmaxf(mx[q], z);
        }
    }
#pragma unroll
    for (int st = 1; st <= 8; st <<= 1)
#pragma unroll
        for (int q = 0; q < 4; q++) mx[q] = fmaxf(mx[q], __shfl_xor(mx[q], st));
    float sm[4] = {0.f, 0.f, 0.f, 0.f};
#pragma unroll
    for (int jt = 0; jt < 13; jt++)
#pragma unroll
        for (int q = 0; q < 4; q++) {
            float e = __expf(ez[jt][q] - mx[q]);
            ez[jt][q] = e;
            sm[q] += e;
        }
#pragma unroll
    for (int st = 1; st <= 8; st <<= 1)
#pragma unroll
        for (int q = 0; q < 4; q++) sm[q] += __shfl_xor(sm[q], st);
    float inv[4];
#pragma unroll
    for (int q = 0; q < 4; q++) inv[q] = 1.f / sm[q];
#pragma unroll
    for (int jt = 0; jt < 13; jt++)
#pragma unroll
        for (int q = 0; q < 4; q++)
            PB[lg * 4 + q][jt * 16 + lrow] = (half_t)(ez[jt][q] * inv[q]);
    __syncthreads();

    const half_t* Vtp = vt + ((long)bh * 64) * 224;
#pragma unroll
    for (int dt = 0; dt < 4; dt++) {
        f32x4 oacc = {};
#pragma unroll
        for (int kt = 0; kt < 7; kt++) {
            half8 pa = *(const half8*)&PB[lrow][kt * 32 + lg * 8];
            half8 vb = *(const half8*)&Vtp[(long)(dt * 16 + lrow) * 224 + kt * 32 + lg * 8];
            oacc = __builtin_amdgcn_mfma_f32_16x16x32_f16(pa, vb, oacc, 0, 0, 0);
        }
#pragma unroll
        for (int q = 0; q < 4; q++) {
            int i = i0 + lg * 4 + q;
            if (i < Nn)
                o[((long)(b * Nn) + i) * INNERc + h * 64 + dt * 16 + lrow] = (half_t)oacc[q];
        }
    }
}

// ---------------- host launcher ----------------
extern "C" void kernel_launch(void* const* d_in, const int* in_sizes, int n_in,
                              void* d_out, int out_size, void* d_ws, size_t ws_size,
                              hipStream_t stream) {
    const float* img     = (const float*)d_in[0];
    const float* patch_g = (const float*)d_in[2];
    const float* patch_b = (const float*)d_in[3];
    const float* W_patch = (const float*)d_in[4];
    const float* b_patch = (const float*)d_in[5];
    const float* emb_g   = (const float*)d_in[6];
    const float* emb_b   = (const float*)d_in[7];
    const float* pos     = (const float*)d_in[8];
    const float* cls     = (const float*)d_in[9];
    const float* ln_g    = (const float*)d_in[10];
    const float* ln_b    = (const float*)d_in[11];
    const float* W_qkv   = (const float*)d_in[12];
    const float* W_out   = (const float*)d_in[13];
    const float* b_out   = (const float*)d_in[14];
    const float* fin_g   = (const float*)d_in[15];
    const float* fin_b   = (const float*)d_in[16];
    const float* W_head  = (const float*)d_in[17];
    const float* b_head  = (const float*)d_in[18];
    float* out = (float*)d_out;

    const long SZ_XD  = (long)Bc * Nn * Dd;            // 4,841,472
    const long SZ_HD  = (long)Bc * NH * Nn * DHd;      // 4,841,472
    const long SZ_VT  = (long)Bc * NH * 64 * 224;      // 5,505,024
    const long SZ_TMP = (long)Bc * NPc * Dd;
    const long SZ_MU  = (long)Bc * 169 * 256 + 1024;   // fragment-layout stats

    float* x    = (float*)d_ws;
    float* tmp  = x + SZ_XD;
    float* muG  = tmp + SZ_TMP;
    float* rsG  = muG + SZ_MU;
    half_t* xh       = (half_t*)(rsG + SZ_MU);
    half_t* qhb      = xh + SZ_XD;
    half_t* khb      = qhb + SZ_HD;
    half_t* vhb      = khb + SZ_HD;
    half_t* vtb      = vhb + SZ_HD;
    half_t* clsh     = vtb + SZ_VT;                         // 32x768 f16
    half_t* wh_head  = clsh + 32 * Dd;                      // 1024x768 f16
    half_t* wt_patch = wh_head + 1024 * Dd;
    half_t* wt_qkv   = wt_patch + (long)Dd * Dd;
    half_t* wt_out   = wt_qkv + (long)DEPTHc * 3 * INNERc * Dd;

    // ---- weight prep ----
    hipLaunchKernelGGL(k_wprep, dim3(Dd / 32, Dd / 32, 1), dim3(32, 8), 0, stream,
                       W_patch, wt_patch, Dd, Dd);
    hipLaunchKernelGGL(k_wprep, dim3(3 * INNERc / 32, Dd / 32, DEPTHc), dim3(32, 8), 0, stream,
                       W_qkv, wt_qkv, Dd, 3 * INNERc);
    hipLaunchKernelGGL(k_wprep, dim3(Dd / 32, Dd / 32, DEPTHc), dim3(32, 8), 0, stream,
                       W_out, wt_out, Dd, Dd);
    hipLaunchKernelGGL(k_wprep_head, dim3(32, 24), dim3(32, 8), 0, stream,
                       W_head, wh_head);

    // 1. patchify + patch LN -> xh (f16)
    hipLaunchKernelGGL(k_patch_ln, dim3(Bc * NPc), dim3(256), 0, stream,
                       img, patch_g, patch_b, xh);
    // 2. patch GEMM (+b_patch) -> tmp fp32
    hipLaunchKernelGGL((k_hgemm<1, 0, float, 0>), dim3(6 * 49), dim3(256), 0, stream,
                       xh, wt_patch, b_patch, nullptr, tmp, nullptr, nullptr,
                       Bc * NPc, Dd, Dd);
    // 3. emb LN + cls concat + pos add -> x
    hipLaunchKernelGGL(k_embed, dim3(Bc * Nn), dim3(256), 0, stream,
                       tmp, cls, pos, emb_g, emb_b, x);

    const int Mrows = Bc * Nn;  // 6304
    for (int l = 0; l < DEPTHc; l++) {
        const float* g  = ln_g + (long)l * Dd;
        const float* bb = ln_b + (long)l * Dd;
        const half_t* Wq = wt_qkv + (long)l * 3 * INNERc * Dd;
        const half_t* Wo = wt_out + (long)l * Dd * Dd;
        const float* bo = b_out + (long)l * Dd;
        hipLaunchKernelGGL((k_ln<half_t>), dim3(Mrows), dim3(256), 0, stream,
                           x, g, bb, xh, (long)Dd, (long)Dd);
        hipLaunchKernelGGL((k_hgemm<0, 0, half_t, 1>), dim3(18 * 50), dim3(256), 0, stream,
                           xh, Wq, nullptr, nullptr, qhb, khb, vhb,
                           Mrows, 3 * INNERc, Dd);
        hipLaunchKernelGGL(k_vtrans, dim3(Bc * NH), dim3(256), 0, stream,
                           vhb, vtb);
        hipLaunchKernelGGL(k_stats, dim3(1352), dim3(256), 0, stream,
                           qhb, khb, (f32x4*)muG, (f32x4*)rsG);
        hipLaunchKernelGGL(k_attn2, dim3(4992), dim3(64), 0, stream,
                           qhb, khb, vtb, (const f32x4*)muG, (const f32x4*)rsG, xh);
        hipLaunchKernelGGL((k_hgemm<1, 1, float, 0>), dim3(6 * 50), dim3(256), 0, stream,
                           xh, Wo, bo, x, x, nullptr, nullptr,
                           Mrows, Dd, Dd);
    }
    // final LN (cls rows only) -> clsh f16
    hipLaunchKernelGGL((k_ln<half_t>), dim3(Bc), dim3(256), 0, stream,
                       x, fin_g, fin_b, clsh, (long)Nn * Dd, (long)Dd);
    // head GEMM: f16 dot per (row,col)
    hipLaunchKernelGGL(k_head, dim3(128), dim3(256), 0, stream,
                       clsh, wh_head, b_head, out);
}